// Round 19
// baseline (231.045 us; speedup 1.0000x reference)
//
#include <hip/hip_runtime.h>
#include <hip/hip_bf16.h>
#include <math.h>

// Shapes: B=1, N=64, L=256, nf=64, npj=32, nfo=128
// All GEMM-shaped work on bf16 MFMA (16x16x32). All intermediate activations bf16.
// Fragment conventions (validated rounds 1-18):
//   A-frag: row = lane&15, k = (lane>>4)*8 + j
//   B-frag: col = lane&15, k = (lane>>4)*8 + j
//   C-frag: col = lane&15, row = (lane>>4)*4 + r
// xdT carries xd/8 so outer products are pre-scaled by 1/64 (exact).
// r18 lesson: expm1f was the hidden elementwise cost (~75us!) -> __expf everywhere.
// r19 = r18 + norm/ELU fused into conv3x3 A-staging (scl/sft cached in LDS this
// time; r17's failure was expm1f + per-element GLOBAL scl/sft loads).

typedef __attribute__((ext_vector_type(8))) short bf16x8;
typedef __attribute__((ext_vector_type(4))) float f32x4;

__device__ __forceinline__ float eluf(float x) { return x > 0.f ? x : __expf(x) - 1.f; }
__device__ __forceinline__ ushort f2b(float f) {
    __hip_bfloat16 h = __float2bfloat16(f);
    return *reinterpret_cast<ushort*>(&h);
}
__device__ __forceinline__ float b2f(ushort u) {
    return __uint_as_float(((unsigned)u) << 16);
}

// ================================================================ mega-prologue
__global__ __launch_bounds__(256) void k_prep(
    const float* __restrict__ msa, const float* __restrict__ W1,
    const float* __restrict__ b1, ushort* __restrict__ xdT,
    const float* __restrict__ W2, const float* __restrict__ g_ln,
    const float* __restrict__ be_ln, const float* __restrict__ b2,
    float* __restrict__ S1, float* __restrict__ S2, ushort* __restrict__ G2swz,
    const float* __restrict__ Wc0, ushort* __restrict__ WCB,
    float* __restrict__ Ai, float* __restrict__ Bl,
    const float* __restrict__ Wr1, ushort* __restrict__ WB1,
    const float* __restrict__ Wr2, ushort* __restrict__ WB2)
{
    __shared__ float smem[32 * 65];
    const int b = blockIdx.x, tid = threadIdx.x;
    if (b < 2048) {
        for (int t = tid; t < 2048; t += 256) smem[(t >> 6) * 65 + (t & 63)] = W1[t];
        __syncthreads();
        const int id = b * 256 + tid;
        const int p = id & 31, l = (id >> 5) & 255, n = id >> 13;
        const float* mrow = msa + (((n << 8) + l) << 6);
        const float* wrow = smem + p * 65;
        float s = 0.f;
#pragma unroll 8
        for (int f = 0; f < 64; ++f) s += mrow[f] * wrow[f];
        xdT[(((l << 5) + p) << 6) + n] = f2b((s + b1[p]) * 0.125f);  // xd/8
    } else if (b < 2176) {
        const int o = b - 2048;
        float s1 = 0.f, s2 = 0.f;
        for (int c = tid; c < 1024; c += 256) {
            float w = W2[o * 1024 + c];
            s1 += g_ln[c] * w;
            s2 += be_ln[c] * w;
        }
#pragma unroll
        for (int off = 32; off; off >>= 1) { s1 += __shfl_down(s1, off); s2 += __shfl_down(s2, off); }
        __shared__ float r1[4], r2[4];
        if ((tid & 63) == 0) { r1[tid >> 6] = s1; r2[tid >> 6] = s2; }
        __syncthreads();
        if (tid == 0) {
            S1[o] = r1[0] + r1[1] + r1[2] + r1[3];
            S2[o] = r2[0] + r2[1] + r2[2] + r2[3] + b2[o];
        }
    } else if (b < 2688) {
        const int idx = (b - 2176) * 256 + tid;   // 131072
        const int j = idx & 7, lane = (idx >> 3) & 63, nt = (idx >> 9) & 7, kt = idx >> 12;
        const int k = kt * 32 + (lane >> 4) * 8 + j;
        const int o = nt * 16 + (lane & 15);
        G2swz[idx] = f2b(g_ln[k] * W2[o * 1024 + k]);
    } else if (b < 2816) {
        const int idx = (b - 2688) * 256 + tid;   // 32768
        const int j = idx & 7, lane = (idx >> 3) & 63, nt = (idx >> 9) & 7, ks = idx >> 12;
        const int ic = ks * 32 + (lane >> 4) * 8 + j;
        const int o = nt * 16 + (lane & 15);
        WCB[idx] = f2b(Wc0[o * 512 + ic]);
    } else if (b < 3072) {
        const int r = b - 2816;
        if (tid < 128) {
            const int c = tid;
            float v;
            if (c < 64) {
                float s = 0.f;
                for (int n = 0; n < 64; ++n) s += msa[(((n << 8) + r) << 6) + c];
                v = s * (1.f / 64.f);
            } else {
                v = msa[(r << 6) + (c - 64)];
            }
            smem[c] = v;
        }
        __syncthreads();
        const int o = tid & 127, half = tid >> 7;
        const float* wv = Wc0 + o * 512 + 256 + (half << 7);
        float a = 0.f;
#pragma unroll 4
        for (int c = 0; c < 128; ++c) a += smem[c] * wv[c];
        (half ? Bl : Ai)[r * 128 + o] = a;
    } else if (b < 3648) {
        const int idx = (b - 3072) * 256 + tid;   // 147456
        const int j = idx & 7, lane = (idx >> 3) & 63, nt = (idx >> 9) & 7;
        const int ks = (idx >> 12) & 3, tap = idx >> 14;
        const int ic = ks * 32 + (lane >> 4) * 8 + j;
        const int o = nt * 16 + (lane & 15);
        WB1[idx] = f2b(Wr1[o * 1152 + ic * 9 + tap]);
    } else {
        const int idx = (b - 3648) * 256 + tid;   // 147456
        const int j = idx & 7, lane = (idx >> 3) & 63, nt = (idx >> 9) & 7;
        const int ks = (idx >> 12) & 3, tap = idx >> 14;
        const int ic = ks * 32 + (lane >> 4) * 8 + j;
        const int o = nt * 16 + (lane & 15);
        WB2[idx] = f2b(Wr2[o * 1152 + ic * 9 + tap]);
    }
}

// ================================================================ fused pair + 1x1 conv (r16/r18)
__global__ __launch_bounds__(256, 2) void k_pairf(
    const ushort* __restrict__ xdT, const ushort* __restrict__ G2swz,
    const float* __restrict__ S1, const float* __restrict__ S2,
    const float* __restrict__ pairo, const float* __restrict__ Ai,
    const float* __restrict__ Bl, const ushort* __restrict__ WCB,
    ushort* __restrict__ X0b, float* __restrict__ ps, float* __restrict__ pq)
{
    __shared__ ushort P_lds[32 * 1024];     // 64 KB; pair2 aliased later
    __shared__ float aibl[12 * 128];        // 6 KB
    __shared__ float mus[32], rstds[32];
    __shared__ float red_s[4][2][16], red_q[4][2][16];
    ushort* pair2_lds = P_lds;              // alias (see barriers)
    const int tid = threadIdx.x;
    const int w = tid >> 6, lane = tid & 63;
    const int lo = lane & 15, kg = lane >> 4;
    const int bid = blockIdx.x;
    const int swz = ((bid & 7) << 8) + (bid >> 3);
    const int lb = (swz & 31) << 3;      // 8 l
    const int ib = (swz >> 5) << 2;      // 4 i
    const int m_w = (w >> 1) << 7;
    const int n_w = (w & 1) << 6;

#pragma unroll
    for (int t = tid; t < 1536; t += 256) {
        if (t < 512) aibl[t] = Ai[((ib + (t >> 7)) << 7) + (t & 127)];
        else         aibl[t] = Bl[((lb + ((t - 512) >> 7)) << 7) + (t & 127)];
    }

    f32x4 acc[8][4] = {};
#pragma unroll
    for (int ks = 0; ks < 2; ++ks) {
        bf16x8 a[8], b[4];
#pragma unroll
        for (int mt = 0; mt < 8; ++mt)
            a[mt] = *(const bf16x8*)&xdT[((lb << 5) + m_w + mt * 16 + lo) * 64 + ks * 32 + kg * 8];
#pragma unroll
        for (int nt = 0; nt < 4; ++nt)
            b[nt] = *(const bf16x8*)&xdT[((ib << 5) + n_w + nt * 16 + lo) * 64 + ks * 32 + kg * 8];
#pragma unroll
        for (int mt = 0; mt < 8; ++mt)
#pragma unroll
            for (int nt = 0; nt < 4; ++nt)
                acc[mt][nt] = __builtin_amdgcn_mfma_f32_16x16x32_bf16(a[mt], b[nt], acc[mt][nt], 0, 0, 0);
    }

#pragma unroll
    for (int jj = 0; jj < 2; ++jj) {
#pragma unroll
        for (int ii = 0; ii < 4; ++ii) {
            float s = 0.f, q = 0.f;
#pragma unroll
            for (int dm = 0; dm < 2; ++dm)
#pragma unroll
                for (int dn = 0; dn < 2; ++dn)
#pragma unroll
                    for (int r = 0; r < 4; ++r) {
                        const float v = acc[ii * 2 + dm][jj * 2 + dn][r];
                        s += v; q += v * v;
                    }
#pragma unroll
            for (int off = 1; off < 64; off <<= 1) { s += __shfl_xor(s, off); q += __shfl_xor(q, off); }
            if (lane == 0) {
                const int l_loc = ((w >> 1) << 2) + ii;
                const int i_loc = ((w & 1) << 1) + jj;
                const int px = (i_loc << 3) + l_loc;
                const float mu = s * (1.f / 1024.f);
                const float var = q * (1.f / 1024.f) - mu * mu;
                mus[px] = mu;
                rstds[px] = rsqrtf(var + 1e-5f);
            }
        }
    }
#pragma unroll
    for (int mt = 0; mt < 8; ++mt) {
        const int mrow = m_w + mt * 16;
        const int l_loc = mrow >> 5;
        const int qb = (mrow & 31) + (kg << 2);
#pragma unroll
        for (int nt = 0; nt < 4; ++nt) {
            const int ncol = n_w + nt * 16;
            const int i_loc = ncol >> 5;
            const int p = (ncol & 31) + lo;
            const int px = (i_loc << 3) + l_loc;
            const int L = (p << 6) + (qb << 1);
            const int phys = (px << 11) + (L ^ ((px & 7) << 4) ^ (((L >> 8) & 3) << 4));
            ushort4 pk;
            pk.x = f2b(acc[mt][nt][0]);
            pk.y = f2b(acc[mt][nt][1]);
            pk.z = f2b(acc[mt][nt][2]);
            pk.w = f2b(acc[mt][nt][3]);
            *(ushort4*)((char*)P_lds + phys) = pk;
        }
    }
    __syncthreads();

    f32x4 pacc[2][2] = {};
#pragma unroll 4
    for (int ks = 0; ks < 32; ++ks) {
        const int L0 = (ks << 6) + (kg << 4);
        const int off0 = (L0 ^ ((lo & 7) << 4) ^ (((L0 >> 8) & 3) << 4));
        const bf16x8 a0 = *(const bf16x8*)((const char*)P_lds + (lo << 11) + off0);
        const bf16x8 a1 = *(const bf16x8*)((const char*)P_lds + ((16 + lo) << 11) + off0);
        const bf16x8 b0 = *(const bf16x8*)&G2swz[(((ks << 3) + (w << 1) + 0) * 64 + lane) * 8];
        const bf16x8 b1 = *(const bf16x8*)&G2swz[(((ks << 3) + (w << 1) + 1) * 64 + lane) * 8];
        pacc[0][0] = __builtin_amdgcn_mfma_f32_16x16x32_bf16(a0, b0, pacc[0][0], 0, 0, 0);
        pacc[0][1] = __builtin_amdgcn_mfma_f32_16x16x32_bf16(a0, b1, pacc[0][1], 0, 0, 0);
        pacc[1][0] = __builtin_amdgcn_mfma_f32_16x16x32_bf16(a1, b0, pacc[1][0], 0, 0, 0);
        pacc[1][1] = __builtin_amdgcn_mfma_f32_16x16x32_bf16(a1, b1, pacc[1][1], 0, 0, 0);
    }
    __syncthreads();   // all P reads done -> safe to alias

#pragma unroll
    for (int mt2 = 0; mt2 < 2; ++mt2) {
#pragma unroll
        for (int j = 0; j < 2; ++j) {
            const int o = (((w << 1) + j) << 4) + lo;
            const float s1v = S1[o], s2v = S2[o];
#pragma unroll
            for (int r = 0; r < 4; ++r) {
                const int px = (mt2 << 4) + (kg << 2) + r;
                const float v = rstds[px] * (pacc[mt2][j][r] - mus[px] * s1v) + s2v;
                const int phys = (px << 8) + ((o << 1) ^ ((px & 7) << 4));
                *(ushort*)((char*)pair2_lds + phys) = f2b(v);
            }
        }
    }
    __syncthreads();

    f32x4 cacc[2][2] = {};
#pragma unroll
    for (int ks2 = 0; ks2 < 8; ++ks2) {
        bf16x8 a[2], b[2];
#pragma unroll
        for (int mt = 0; mt < 2; ++mt) {
            const int px = mt * 16 + lo;
            if (ks2 < 4) {
                const int pix = ((ib + (px >> 3)) << 8) + lb + (px & 7);
                const float* base = &pairo[pix * 128 + (ks2 & 3) * 32 + kg * 8];
                const uint4 u0 = *(const uint4*)base;
                const uint4 u1 = *(const uint4*)(base + 4);
                uint4 pk;
                pk.x = __builtin_amdgcn_perm(u0.y, u0.x, 0x07060302);
                pk.y = __builtin_amdgcn_perm(u0.w, u0.z, 0x07060302);
                pk.z = __builtin_amdgcn_perm(u1.y, u1.x, 0x07060302);
                pk.w = __builtin_amdgcn_perm(u1.w, u1.z, 0x07060302);
                a[mt] = *(const bf16x8*)&pk;
            } else {
                const int L0 = ((ks2 & 3) << 6) + (kg << 4);
                const int phys = (px << 8) + (L0 ^ ((px & 7) << 4));
                a[mt] = *(const bf16x8*)((const char*)pair2_lds + phys);
            }
        }
#pragma unroll
        for (int j = 0; j < 2; ++j)
            b[j] = *(const bf16x8*)&WCB[(((ks2 << 3) + (w << 1) + j) * 64 + lane) * 8];
#pragma unroll
        for (int mt = 0; mt < 2; ++mt)
#pragma unroll
            for (int j = 0; j < 2; ++j)
                cacc[mt][j] = __builtin_amdgcn_mfma_f32_16x16x32_bf16(a[mt], b[j], cacc[mt][j], 0, 0, 0);
    }

    float lsum[2] = {0.f, 0.f}, lsq[2] = {0.f, 0.f};
#pragma unroll
    for (int j = 0; j < 2; ++j) {
        const int o = (((w << 1) + j) << 4) + lo;
#pragma unroll
        for (int mt = 0; mt < 2; ++mt) {
#pragma unroll
            for (int r = 0; r < 4; ++r) {
                const int px = mt * 16 + kg * 4 + r;
                const int i_loc = px >> 3, l_loc = px & 7;
                const float v = cacc[mt][j][r] + aibl[(i_loc << 7) + o] + aibl[512 + (l_loc << 7) + o];
                const int pix = ((ib + i_loc) << 8) + lb + l_loc;
                X0b[(pix << 7) + o] = f2b(v);
                lsum[j] += v; lsq[j] += v * v;
            }
        }
    }
#pragma unroll
    for (int j = 0; j < 2; ++j) {
        lsum[j] += __shfl_xor(lsum[j], 16); lsum[j] += __shfl_xor(lsum[j], 32);
        lsq[j]  += __shfl_xor(lsq[j], 16);  lsq[j]  += __shfl_xor(lsq[j], 32);
    }
    if (kg == 0) {
#pragma unroll
        for (int j = 0; j < 2; ++j) { red_s[w][j][lo] = lsum[j]; red_q[w][j][lo] = lsq[j]; }
    }
    __syncthreads();
    if (tid < 128) {
        const int o = tid;
        const int w2 = o >> 5, j2 = (o >> 4) & 1, lo2 = o & 15;
        ps[swz * 128 + o] = red_s[w2][j2][lo2];
        pq[swz * 128 + o] = red_q[w2][j2][lo2];
    }
}

// ================================================================ 3x3 conv v7: LDS-staged + fused norm/ELU
// scl/sft cached in LDS (read ONCE); staging applies elu(x*scl+sft) with __expf.
// OOB stays exact 0 (pad-after-norm semantics).
__global__ __launch_bounds__(256, 1) void k_conv3x3m(
    const ushort* __restrict__ Xb, const ushort* __restrict__ WB,
    const float* __restrict__ scl, const float* __restrict__ sft,
    ushort* __restrict__ outb, float* __restrict__ ps, float* __restrict__ pq)
{
    __shared__ ushort A_lds[3 * 130 * 136];   // 106,080 B (272 B per px)
    __shared__ ushort Bbuf[3 * 4096];         // 24,576 B
    __shared__ float red_s[4][4][16], red_q[4][4][16];
    __shared__ float sclS[128], sftS[128];
    const int tid = threadIdx.x;
    const int w = tid >> 6, lane = tid & 63;
    const int lo = lane & 15, kg = lane >> 4;
    const int m_w = (w >> 1) << 6;
    const int n4 = (w & 1) << 2;
    const int n_w = (w & 1) << 6;
    const int bid = blockIdx.x;
    const int swz = ((bid & 7) << 6) + (bid >> 3);
    const int y = swz >> 1;
    const int x0 = (swz & 1) << 7;

    if (tid < 128) { sclS[tid] = scl[tid]; sftS[tid] = sft[tid]; }
    __syncthreads();

    // stage A with fused norm+ELU (scl/sft from LDS)
    for (int s = tid; s < 6240; s += 256) {
        const int c16 = s & 15;
        const int t2 = s >> 4;
        const int pl = t2 % 130;
        const int ky = t2 / 130;
        const int gx = x0 - 1 + pl;
        const int gy = y - 1 + ky;
        uint4 v = make_uint4(0u, 0u, 0u, 0u);
        if ((unsigned)gx < 256u && (unsigned)gy < 256u) {
            const uint4 raw = *(const uint4*)&Xb[(((gy << 8) + gx) << 7) + (c16 << 3)];
            const ushort* u = (const ushort*)&raw;
            const int c0 = c16 << 3;
            ushort ro[8];
#pragma unroll
            for (int t = 0; t < 8; ++t)
                ro[t] = f2b(eluf(b2f(u[t]) * sclS[c0 + t] + sftS[c0 + t]));
            v = *(const uint4*)ro;
        }
        *(uint4*)((char*)A_lds + ky * 35360 + pl * 272 + (c16 << 4)) = v;
    }
    {
        uint4 r0a = *(const uint4*)&WB[0 * 4096 + (tid << 4)];
        uint4 r0b = *(const uint4*)&WB[0 * 4096 + (tid << 4) + 8];
        uint4 r1a = *(const uint4*)&WB[1 * 4096 + (tid << 4)];
        uint4 r1b = *(const uint4*)&WB[1 * 4096 + (tid << 4) + 8];
        *(uint4*)&Bbuf[0 * 4096 + (tid << 4)] = r0a;
        *(uint4*)&Bbuf[0 * 4096 + (tid << 4) + 8] = r0b;
        *(uint4*)&Bbuf[1 * 4096 + (tid << 4)] = r1a;
        *(uint4*)&Bbuf[1 * 4096 + (tid << 4) + 8] = r1b;
    }
    __syncthreads();

    f32x4 acc[4][4] = {};
#pragma unroll
    for (int s = 0; s < 36; ++s) {
        const int tap = s >> 2, ks = s & 3;
        const int ky = tap / 3, kx = tap % 3;
        uint4 pba, pbb;
        if (s + 2 < 36) {
            pba = *(const uint4*)&WB[(s + 2) * 4096 + (tid << 4)];
            pbb = *(const uint4*)&WB[(s + 2) * 4096 + (tid << 4) + 8];
        }
        bf16x8 a[4], b[4];
#pragma unroll
        for (int mt = 0; mt < 4; ++mt) {
            const int pl = m_w + mt * 16 + lo + kx;
            a[mt] = *(const bf16x8*)((const char*)A_lds + ky * 35360 + pl * 272 + ks * 64 + kg * 16);
        }
#pragma unroll
        for (int nt = 0; nt < 4; ++nt)
            b[nt] = *(const bf16x8*)&Bbuf[(s % 3) * 4096 + (n4 + nt) * 512 + lane * 8];
#pragma unroll
        for (int mt = 0; mt < 4; ++mt)
#pragma unroll
            for (int nt = 0; nt < 4; ++nt)
                acc[mt][nt] = __builtin_amdgcn_mfma_f32_16x16x32_bf16(a[mt], b[nt], acc[mt][nt], 0, 0, 0);
        if (s + 2 < 36) {
            *(uint4*)&Bbuf[((s + 2) % 3) * 4096 + (tid << 4)] = pba;
            *(uint4*)&Bbuf[((s + 2) % 3) * 4096 + (tid << 4) + 8] = pbb;
        }
        __syncthreads();
    }

    float lsum[4] = {0.f, 0.f, 0.f, 0.f}, lsq[4] = {0.f, 0.f, 0.f, 0.f};
#pragma unroll
    for (int nt = 0; nt < 4; ++nt) {
        const int o = n_w + nt * 16 + lo;
#pragma unroll
        for (int mt = 0; mt < 4; ++mt) {
#pragma unroll
            for (int r = 0; r < 4; ++r) {
                const int xo = x0 + m_w + mt * 16 + kg * 4 + r;
                const float v = acc[mt][nt][r];
                outb[(((y << 8) + xo) << 7) + o] = f2b(v);
                lsum[nt] += v; lsq[nt] += v * v;
            }
        }
    }
#pragma unroll
    for (int nt = 0; nt < 4; ++nt) {
        lsum[nt] += __shfl_xor(lsum[nt], 16); lsum[nt] += __shfl_xor(lsum[nt], 32);
        lsq[nt]  += __shfl_xor(lsq[nt], 16);  lsq[nt]  += __shfl_xor(lsq[nt], 32);
    }
    if (kg == 0) {
#pragma unroll
        for (int nt = 0; nt < 4; ++nt) { red_s[w][nt][lo] = lsum[nt]; red_q[w][nt][lo] = lsq[nt]; }
    }
    __syncthreads();
    if (tid < 128) {
        const int o = tid;
        const int half = o >> 6, nt = (o & 63) >> 4, lo2 = o & 15;
        const float s = red_s[half][nt][lo2] + red_s[half + 2][nt][lo2];
        const float q = red_q[half][nt][lo2] + red_q[half + 2][nt][lo2];
        ps[swz * 128 + o] = s;
        pq[swz * 128 + o] = q;
    }
}

// ------------------------------------------- per-channel IN params
__global__ __launch_bounds__(256) void k_stats(
    const float* __restrict__ ps, const float* __restrict__ pq, int R,
    const float* __restrict__ g, const float* __restrict__ be,
    float* __restrict__ scl, float* __restrict__ sft)
{
    const int o = blockIdx.x, tid = threadIdx.x;
    float s = 0.f, q = 0.f;
    for (int r = tid; r < R; r += 256) { s += ps[r * 128 + o]; q += pq[r * 128 + o]; }
#pragma unroll
    for (int off = 32; off; off >>= 1) { s += __shfl_down(s, off); q += __shfl_down(q, off); }
    __shared__ float rs[4], rq[4];
    if ((tid & 63) == 0) { rs[tid >> 6] = s; rq[tid >> 6] = q; }
    __syncthreads();
    if (tid == 0) {
        s = rs[0] + rs[1] + rs[2] + rs[3];
        q = rq[0] + rq[1] + rq[2] + rq[3];
        const float mean = s * (1.f / 65536.f);
        const float var = q * (1.f / 65536.f) - mean * mean;
        const float rstd = rsqrtf(var + 1e-6f);
        const float sc = g[o] * rstd;
        scl[o] = sc;
        sft[o] = be[o] - mean * sc;
    }
}

// ------------------------------------------- final: out = elu(elu(x0*s0+f0) + h2*s2+f2), fp32
__global__ __launch_bounds__(256) void k_final(
    const ushort* __restrict__ x0b, const ushort* __restrict__ h2b,
    const float* __restrict__ scl0, const float* __restrict__ sft0,
    const float* __restrict__ scl2, const float* __restrict__ sft2,
    float* __restrict__ outp)
{
    const int j = blockIdx.x * 256 + threadIdx.x;   // 1048576 groups of 8
    const uint4 xv = ((const uint4*)x0b)[j];
    const uint4 hv = ((const uint4*)h2b)[j];
    const ushort* xu = (const ushort*)&xv;
    const ushort* hu = (const ushort*)&hv;
    const int o0 = (j & 15) << 3;
    float ro[8];
#pragma unroll
    for (int t = 0; t < 8; ++t) {
        const float x1 = eluf(b2f(xu[t]) * scl0[o0 + t] + sft0[o0 + t]);
        const float h = b2f(hu[t]);
        ro[t] = eluf(x1 + h * scl2[o0 + t] + sft2[o0 + t]);
    }
    ((float4*)outp)[2 * j]     = *(const float4*)&ro[0];
    ((float4*)outp)[2 * j + 1] = *(const float4*)&ro[4];
}

extern "C" void kernel_launch(void* const* d_in, const int* in_sizes, int n_in,
                              void* d_out, int out_size, void* d_ws, size_t ws_size,
                              hipStream_t stream)
{
    const float* msa   = (const float*)d_in[0];
    const float* pairo = (const float*)d_in[1];
    const float* W1    = (const float*)d_in[2];
    const float* b1    = (const float*)d_in[3];
    const float* g_ln  = (const float*)d_in[4];
    const float* be_ln = (const float*)d_in[5];
    const float* W2    = (const float*)d_in[6];
    const float* b2    = (const float*)d_in[7];
    const float* Wc0   = (const float*)d_in[8];
    const float* g0    = (const float*)d_in[9];
    const float* be0   = (const float*)d_in[10];
    const float* Wr1   = (const float*)d_in[11];
    const float* g1    = (const float*)d_in[12];
    const float* be1   = (const float*)d_in[13];
    const float* Wr2   = (const float*)d_in[14];
    const float* g2    = (const float*)d_in[15];
    const float* be2   = (const float*)d_in[16];

    float* ws = (float*)d_ws;
    ushort* xdT   = (ushort*)ws;                    // 262144 f
    float* Ai     = ws + 294912;                    // 32768
    float* Bl     = ws + 327680;                    // 32768
    float* S1     = ws + 360448;                    // 128
    float* S2     = ws + 360576;                    // 128
    float* scl0   = ws + 360704;                    // 128
    float* sft0   = ws + 360832;                    // 128
    float* scl1   = ws + 360960;                    // 128
    float* sft1   = ws + 361088;                    // 128
    float* scl2   = ws + 361216;                    // 128
    float* sft2   = ws + 361344;                    // 128
    ushort* WCB   = (ushort*)(ws + 361472);         // 16384 f
    ushort* G2swz = (ushort*)(ws + 393728);         // 65536 f
    float* ps     = ws + 590336;                    // 524288
    float* pq     = ws + 1114624;                   // 524288
    ushort* WB1   = (ushort*)(ws + 1638912);        // 73728 f
    ushort* WB2   = (ushort*)(ws + 1712640);        // 73728 f
    float* R1     = ws + 1786368;                   // 8388608 f
    float* R2     = ws + 10174976;                  // 8388608 f
    ushort* H2b = (ushort*)R1;                      // R1 lo
    ushort* X0b = (ushort*)R2;                      // R2 lo
    ushort* Hb  = (ushort*)(R2 + 4194304);          // R2 hi

    k_prep<<<dim3(4224), dim3(256), 0, stream>>>(
        msa, W1, b1, xdT, W2, g_ln, be_ln, b2, S1, S2, G2swz,
        Wc0, WCB, Ai, Bl, Wr1, WB1, Wr2, WB2);

    k_pairf<<<dim3(2048), dim3(256), 0, stream>>>(
        xdT, G2swz, S1, S2, pairo, Ai, Bl, WCB, X0b, ps, pq);

    k_stats<<<dim3(128), dim3(256), 0, stream>>>(ps, pq, 2048, g0, be0, scl0, sft0);

    k_conv3x3m<<<dim3(512), dim3(256), 0, stream>>>(X0b, WB1, scl0, sft0, Hb, ps, pq);
    k_stats<<<dim3(128), dim3(256), 0, stream>>>(ps, pq, 512, g1, be1, scl1, sft1);

    k_conv3x3m<<<dim3(512), dim3(256), 0, stream>>>(Hb, WB2, scl1, sft1, H2b, ps, pq);
    k_stats<<<dim3(128), dim3(256), 0, stream>>>(ps, pq, 512, g2, be2, scl2, sft2);

    k_final<<<dim3(4096), dim3(256), 0, stream>>>(X0b, H2b, scl0, sft0, scl2, sft2, (float*)d_out);
}

// Round 20
// 224.639 us; speedup vs baseline: 1.0285x; 1.0285x over previous
//
#include <hip/hip_runtime.h>
#include <hip/hip_bf16.h>
#include <math.h>

// Shapes: B=1, N=64, L=256, nf=64, npj=32, nfo=128
// All GEMM-shaped work on bf16 MFMA (16x16x32). All intermediate activations bf16.
// Fragment conventions (validated rounds 1-19):
//   A-frag: row = lane&15, k = (lane>>4)*8 + j
//   B-frag: col = lane&15, k = (lane>>4)*8 + j
//   C-frag: col = lane&15, row = (lane>>4)*4 + r
// xdT carries xd/8 so outer products are pre-scaled by 1/64 (exact).
// r18 lesson: expm1f was ~75us of hidden elementwise cost -> __expf.
// r19 lesson: norm/ELU fusion into 1-wave/SIMD conv staging is net-negative -> keep separate.
// r20: conv3x3m v8 — B LDS buffer + its 36 in-loop barriers REMOVED; B direct from
// L2 via 3-slot register pipeline; A stays in staged LDS (read-only, 1 barrier).

typedef __attribute__((ext_vector_type(8))) short bf16x8;
typedef __attribute__((ext_vector_type(4))) float f32x4;

__device__ __forceinline__ float eluf(float x) { return x > 0.f ? x : __expf(x) - 1.f; }
__device__ __forceinline__ ushort f2b(float f) {
    __hip_bfloat16 h = __float2bfloat16(f);
    return *reinterpret_cast<ushort*>(&h);
}
__device__ __forceinline__ float b2f(ushort u) {
    return __uint_as_float(((unsigned)u) << 16);
}

// ================================================================ mega-prologue
__global__ __launch_bounds__(256) void k_prep(
    const float* __restrict__ msa, const float* __restrict__ W1,
    const float* __restrict__ b1, ushort* __restrict__ xdT,
    const float* __restrict__ W2, const float* __restrict__ g_ln,
    const float* __restrict__ be_ln, const float* __restrict__ b2,
    float* __restrict__ S1, float* __restrict__ S2, ushort* __restrict__ G2swz,
    const float* __restrict__ Wc0, ushort* __restrict__ WCB,
    float* __restrict__ Ai, float* __restrict__ Bl,
    const float* __restrict__ Wr1, ushort* __restrict__ WB1,
    const float* __restrict__ Wr2, ushort* __restrict__ WB2)
{
    __shared__ float smem[32 * 65];
    const int b = blockIdx.x, tid = threadIdx.x;
    if (b < 2048) {
        for (int t = tid; t < 2048; t += 256) smem[(t >> 6) * 65 + (t & 63)] = W1[t];
        __syncthreads();
        const int id = b * 256 + tid;
        const int p = id & 31, l = (id >> 5) & 255, n = id >> 13;
        const float* mrow = msa + (((n << 8) + l) << 6);
        const float* wrow = smem + p * 65;
        float s = 0.f;
#pragma unroll 8
        for (int f = 0; f < 64; ++f) s += mrow[f] * wrow[f];
        xdT[(((l << 5) + p) << 6) + n] = f2b((s + b1[p]) * 0.125f);  // xd/8
    } else if (b < 2176) {
        const int o = b - 2048;
        float s1 = 0.f, s2 = 0.f;
        for (int c = tid; c < 1024; c += 256) {
            float w = W2[o * 1024 + c];
            s1 += g_ln[c] * w;
            s2 += be_ln[c] * w;
        }
#pragma unroll
        for (int off = 32; off; off >>= 1) { s1 += __shfl_down(s1, off); s2 += __shfl_down(s2, off); }
        __shared__ float r1[4], r2[4];
        if ((tid & 63) == 0) { r1[tid >> 6] = s1; r2[tid >> 6] = s2; }
        __syncthreads();
        if (tid == 0) {
            S1[o] = r1[0] + r1[1] + r1[2] + r1[3];
            S2[o] = r2[0] + r2[1] + r2[2] + r2[3] + b2[o];
        }
    } else if (b < 2688) {
        const int idx = (b - 2176) * 256 + tid;   // 131072
        const int j = idx & 7, lane = (idx >> 3) & 63, nt = (idx >> 9) & 7, kt = idx >> 12;
        const int k = kt * 32 + (lane >> 4) * 8 + j;
        const int o = nt * 16 + (lane & 15);
        G2swz[idx] = f2b(g_ln[k] * W2[o * 1024 + k]);
    } else if (b < 2816) {
        const int idx = (b - 2688) * 256 + tid;   // 32768
        const int j = idx & 7, lane = (idx >> 3) & 63, nt = (idx >> 9) & 7, ks = idx >> 12;
        const int ic = ks * 32 + (lane >> 4) * 8 + j;
        const int o = nt * 16 + (lane & 15);
        WCB[idx] = f2b(Wc0[o * 512 + ic]);
    } else if (b < 3072) {
        const int r = b - 2816;
        if (tid < 128) {
            const int c = tid;
            float v;
            if (c < 64) {
                float s = 0.f;
                for (int n = 0; n < 64; ++n) s += msa[(((n << 8) + r) << 6) + c];
                v = s * (1.f / 64.f);
            } else {
                v = msa[(r << 6) + (c - 64)];
            }
            smem[c] = v;
        }
        __syncthreads();
        const int o = tid & 127, half = tid >> 7;
        const float* wv = Wc0 + o * 512 + 256 + (half << 7);
        float a = 0.f;
#pragma unroll 4
        for (int c = 0; c < 128; ++c) a += smem[c] * wv[c];
        (half ? Bl : Ai)[r * 128 + o] = a;
    } else if (b < 3648) {
        const int idx = (b - 3072) * 256 + tid;   // 147456
        const int j = idx & 7, lane = (idx >> 3) & 63, nt = (idx >> 9) & 7;
        const int ks = (idx >> 12) & 3, tap = idx >> 14;
        const int ic = ks * 32 + (lane >> 4) * 8 + j;
        const int o = nt * 16 + (lane & 15);
        WB1[idx] = f2b(Wr1[o * 1152 + ic * 9 + tap]);
    } else {
        const int idx = (b - 3648) * 256 + tid;   // 147456
        const int j = idx & 7, lane = (idx >> 3) & 63, nt = (idx >> 9) & 7;
        const int ks = (idx >> 12) & 3, tap = idx >> 14;
        const int ic = ks * 32 + (lane >> 4) * 8 + j;
        const int o = nt * 16 + (lane & 15);
        WB2[idx] = f2b(Wr2[o * 1152 + ic * 9 + tap]);
    }
}

// ================================================================ fused pair + 1x1 conv (r16/r18)
__global__ __launch_bounds__(256, 2) void k_pairf(
    const ushort* __restrict__ xdT, const ushort* __restrict__ G2swz,
    const float* __restrict__ S1, const float* __restrict__ S2,
    const float* __restrict__ pairo, const float* __restrict__ Ai,
    const float* __restrict__ Bl, const ushort* __restrict__ WCB,
    ushort* __restrict__ X0b, float* __restrict__ ps, float* __restrict__ pq)
{
    __shared__ ushort P_lds[32 * 1024];     // 64 KB; pair2 aliased later
    __shared__ float aibl[12 * 128];        // 6 KB
    __shared__ float mus[32], rstds[32];
    __shared__ float red_s[4][2][16], red_q[4][2][16];
    ushort* pair2_lds = P_lds;              // alias (see barriers)
    const int tid = threadIdx.x;
    const int w = tid >> 6, lane = tid & 63;
    const int lo = lane & 15, kg = lane >> 4;
    const int bid = blockIdx.x;
    const int swz = ((bid & 7) << 8) + (bid >> 3);
    const int lb = (swz & 31) << 3;      // 8 l
    const int ib = (swz >> 5) << 2;      // 4 i
    const int m_w = (w >> 1) << 7;
    const int n_w = (w & 1) << 6;

#pragma unroll
    for (int t = tid; t < 1536; t += 256) {
        if (t < 512) aibl[t] = Ai[((ib + (t >> 7)) << 7) + (t & 127)];
        else         aibl[t] = Bl[((lb + ((t - 512) >> 7)) << 7) + (t & 127)];
    }

    f32x4 acc[8][4] = {};
#pragma unroll
    for (int ks = 0; ks < 2; ++ks) {
        bf16x8 a[8], b[4];
#pragma unroll
        for (int mt = 0; mt < 8; ++mt)
            a[mt] = *(const bf16x8*)&xdT[((lb << 5) + m_w + mt * 16 + lo) * 64 + ks * 32 + kg * 8];
#pragma unroll
        for (int nt = 0; nt < 4; ++nt)
            b[nt] = *(const bf16x8*)&xdT[((ib << 5) + n_w + nt * 16 + lo) * 64 + ks * 32 + kg * 8];
#pragma unroll
        for (int mt = 0; mt < 8; ++mt)
#pragma unroll
            for (int nt = 0; nt < 4; ++nt)
                acc[mt][nt] = __builtin_amdgcn_mfma_f32_16x16x32_bf16(a[mt], b[nt], acc[mt][nt], 0, 0, 0);
    }

#pragma unroll
    for (int jj = 0; jj < 2; ++jj) {
#pragma unroll
        for (int ii = 0; ii < 4; ++ii) {
            float s = 0.f, q = 0.f;
#pragma unroll
            for (int dm = 0; dm < 2; ++dm)
#pragma unroll
                for (int dn = 0; dn < 2; ++dn)
#pragma unroll
                    for (int r = 0; r < 4; ++r) {
                        const float v = acc[ii * 2 + dm][jj * 2 + dn][r];
                        s += v; q += v * v;
                    }
#pragma unroll
            for (int off = 1; off < 64; off <<= 1) { s += __shfl_xor(s, off); q += __shfl_xor(q, off); }
            if (lane == 0) {
                const int l_loc = ((w >> 1) << 2) + ii;
                const int i_loc = ((w & 1) << 1) + jj;
                const int px = (i_loc << 3) + l_loc;
                const float mu = s * (1.f / 1024.f);
                const float var = q * (1.f / 1024.f) - mu * mu;
                mus[px] = mu;
                rstds[px] = rsqrtf(var + 1e-5f);
            }
        }
    }
#pragma unroll
    for (int mt = 0; mt < 8; ++mt) {
        const int mrow = m_w + mt * 16;
        const int l_loc = mrow >> 5;
        const int qb = (mrow & 31) + (kg << 2);
#pragma unroll
        for (int nt = 0; nt < 4; ++nt) {
            const int ncol = n_w + nt * 16;
            const int i_loc = ncol >> 5;
            const int p = (ncol & 31) + lo;
            const int px = (i_loc << 3) + l_loc;
            const int L = (p << 6) + (qb << 1);
            const int phys = (px << 11) + (L ^ ((px & 7) << 4) ^ (((L >> 8) & 3) << 4));
            ushort4 pk;
            pk.x = f2b(acc[mt][nt][0]);
            pk.y = f2b(acc[mt][nt][1]);
            pk.z = f2b(acc[mt][nt][2]);
            pk.w = f2b(acc[mt][nt][3]);
            *(ushort4*)((char*)P_lds + phys) = pk;
        }
    }
    __syncthreads();

    f32x4 pacc[2][2] = {};
#pragma unroll 4
    for (int ks = 0; ks < 32; ++ks) {
        const int L0 = (ks << 6) + (kg << 4);
        const int off0 = (L0 ^ ((lo & 7) << 4) ^ (((L0 >> 8) & 3) << 4));
        const bf16x8 a0 = *(const bf16x8*)((const char*)P_lds + (lo << 11) + off0);
        const bf16x8 a1 = *(const bf16x8*)((const char*)P_lds + ((16 + lo) << 11) + off0);
        const bf16x8 b0 = *(const bf16x8*)&G2swz[(((ks << 3) + (w << 1) + 0) * 64 + lane) * 8];
        const bf16x8 b1 = *(const bf16x8*)&G2swz[(((ks << 3) + (w << 1) + 1) * 64 + lane) * 8];
        pacc[0][0] = __builtin_amdgcn_mfma_f32_16x16x32_bf16(a0, b0, pacc[0][0], 0, 0, 0);
        pacc[0][1] = __builtin_amdgcn_mfma_f32_16x16x32_bf16(a0, b1, pacc[0][1], 0, 0, 0);
        pacc[1][0] = __builtin_amdgcn_mfma_f32_16x16x32_bf16(a1, b0, pacc[1][0], 0, 0, 0);
        pacc[1][1] = __builtin_amdgcn_mfma_f32_16x16x32_bf16(a1, b1, pacc[1][1], 0, 0, 0);
    }
    __syncthreads();   // all P reads done -> safe to alias

#pragma unroll
    for (int mt2 = 0; mt2 < 2; ++mt2) {
#pragma unroll
        for (int j = 0; j < 2; ++j) {
            const int o = (((w << 1) + j) << 4) + lo;
            const float s1v = S1[o], s2v = S2[o];
#pragma unroll
            for (int r = 0; r < 4; ++r) {
                const int px = (mt2 << 4) + (kg << 2) + r;
                const float v = rstds[px] * (pacc[mt2][j][r] - mus[px] * s1v) + s2v;
                const int phys = (px << 8) + ((o << 1) ^ ((px & 7) << 4));
                *(ushort*)((char*)pair2_lds + phys) = f2b(v);
            }
        }
    }
    __syncthreads();

    f32x4 cacc[2][2] = {};
#pragma unroll
    for (int ks2 = 0; ks2 < 8; ++ks2) {
        bf16x8 a[2], b[2];
#pragma unroll
        for (int mt = 0; mt < 2; ++mt) {
            const int px = mt * 16 + lo;
            if (ks2 < 4) {
                const int pix = ((ib + (px >> 3)) << 8) + lb + (px & 7);
                const float* base = &pairo[pix * 128 + (ks2 & 3) * 32 + kg * 8];
                const uint4 u0 = *(const uint4*)base;
                const uint4 u1 = *(const uint4*)(base + 4);
                uint4 pk;
                pk.x = __builtin_amdgcn_perm(u0.y, u0.x, 0x07060302);
                pk.y = __builtin_amdgcn_perm(u0.w, u0.z, 0x07060302);
                pk.z = __builtin_amdgcn_perm(u1.y, u1.x, 0x07060302);
                pk.w = __builtin_amdgcn_perm(u1.w, u1.z, 0x07060302);
                a[mt] = *(const bf16x8*)&pk;
            } else {
                const int L0 = ((ks2 & 3) << 6) + (kg << 4);
                const int phys = (px << 8) + (L0 ^ ((px & 7) << 4));
                a[mt] = *(const bf16x8*)((const char*)pair2_lds + phys);
            }
        }
#pragma unroll
        for (int j = 0; j < 2; ++j)
            b[j] = *(const bf16x8*)&WCB[(((ks2 << 3) + (w << 1) + j) * 64 + lane) * 8];
#pragma unroll
        for (int mt = 0; mt < 2; ++mt)
#pragma unroll
            for (int j = 0; j < 2; ++j)
                cacc[mt][j] = __builtin_amdgcn_mfma_f32_16x16x32_bf16(a[mt], b[j], cacc[mt][j], 0, 0, 0);
    }

    float lsum[2] = {0.f, 0.f}, lsq[2] = {0.f, 0.f};
#pragma unroll
    for (int j = 0; j < 2; ++j) {
        const int o = (((w << 1) + j) << 4) + lo;
#pragma unroll
        for (int mt = 0; mt < 2; ++mt) {
#pragma unroll
            for (int r = 0; r < 4; ++r) {
                const int px = mt * 16 + kg * 4 + r;
                const int i_loc = px >> 3, l_loc = px & 7;
                const float v = cacc[mt][j][r] + aibl[(i_loc << 7) + o] + aibl[512 + (l_loc << 7) + o];
                const int pix = ((ib + i_loc) << 8) + lb + l_loc;
                X0b[(pix << 7) + o] = f2b(v);
                lsum[j] += v; lsq[j] += v * v;
            }
        }
    }
#pragma unroll
    for (int j = 0; j < 2; ++j) {
        lsum[j] += __shfl_xor(lsum[j], 16); lsum[j] += __shfl_xor(lsum[j], 32);
        lsq[j]  += __shfl_xor(lsq[j], 16);  lsq[j]  += __shfl_xor(lsq[j], 32);
    }
    if (kg == 0) {
#pragma unroll
        for (int j = 0; j < 2; ++j) { red_s[w][j][lo] = lsum[j]; red_q[w][j][lo] = lsq[j]; }
    }
    __syncthreads();
    if (tid < 128) {
        const int o = tid;
        const int w2 = o >> 5, j2 = (o >> 4) & 1, lo2 = o & 15;
        ps[swz * 128 + o] = red_s[w2][j2][lo2];
        pq[swz * 128 + o] = red_q[w2][j2][lo2];
    }
}

// ================================================================ 3x3 conv v8: A in LDS (1 barrier),
// B direct from L2 via 3-slot register pipeline, ZERO barriers in the K-loop.
__global__ __launch_bounds__(256, 1) void k_conv3x3m(
    const ushort* __restrict__ Xb, const ushort* __restrict__ WB,
    ushort* __restrict__ outb, float* __restrict__ ps, float* __restrict__ pq)
{
    __shared__ ushort A_lds[3 * 130 * 136];   // 106,080 B (272 B per px)
    __shared__ float red_s[4][4][16], red_q[4][4][16];
    const int tid = threadIdx.x;
    const int w = tid >> 6, lane = tid & 63;
    const int lo = lane & 15, kg = lane >> 4;
    const int m_w = (w >> 1) << 6;
    const int n4 = (w & 1) << 2;
    const int n_w = (w & 1) << 6;
    const int bid = blockIdx.x;
    const int swz = ((bid & 7) << 6) + (bid >> 3);
    const int y = swz >> 1;
    const int x0 = (swz & 1) << 7;

    // stage A once (OOB = 0)
    for (int s = tid; s < 6240; s += 256) {
        const int c16 = s & 15;
        const int t2 = s >> 4;
        const int pl = t2 % 130;
        const int ky = t2 / 130;
        const int gx = x0 - 1 + pl;
        const int gy = y - 1 + ky;
        uint4 v = make_uint4(0u, 0u, 0u, 0u);
        if ((unsigned)gx < 256u && (unsigned)gy < 256u)
            v = *(const uint4*)&Xb[(((gy << 8) + gx) << 7) + (c16 << 3)];
        *(uint4*)((char*)A_lds + ky * 35360 + pl * 272 + (c16 << 4)) = v;
    }
    __syncthreads();   // the ONLY barrier before the epilogue

    f32x4 acc[4][4] = {};
    bf16x8 B[3][4];
#define BLOAD(S, SL)                                                                  \
    {                                                                                 \
        _Pragma("unroll")                                                             \
        for (int nt = 0; nt < 4; ++nt)                                                \
            B[SL][nt] = *(const bf16x8*)&WB[(S) * 4096 + (n4 + nt) * 512 + lane * 8]; \
    }
    BLOAD(0, 0);
    BLOAD(1, 1);
#pragma unroll
    for (int s = 0; s < 36; ++s) {
        const int tap = s >> 2, ks = s & 3;
        const int ky = tap / 3, kx = tap % 3;
        if (s + 2 < 36) BLOAD(s + 2, (s + 2) % 3);
        bf16x8 a[4];
#pragma unroll
        for (int mt = 0; mt < 4; ++mt) {
            const int pl = m_w + mt * 16 + lo + kx;
            a[mt] = *(const bf16x8*)((const char*)A_lds + ky * 35360 + pl * 272 + ks * 64 + kg * 16);
        }
#pragma unroll
        for (int mt = 0; mt < 4; ++mt)
#pragma unroll
            for (int nt = 0; nt < 4; ++nt)
                acc[mt][nt] = __builtin_amdgcn_mfma_f32_16x16x32_bf16(a[mt], B[s % 3][nt], acc[mt][nt], 0, 0, 0);
    }
#undef BLOAD

    float lsum[4] = {0.f, 0.f, 0.f, 0.f}, lsq[4] = {0.f, 0.f, 0.f, 0.f};
#pragma unroll
    for (int nt = 0; nt < 4; ++nt) {
        const int o = n_w + nt * 16 + lo;
#pragma unroll
        for (int mt = 0; mt < 4; ++mt) {
#pragma unroll
            for (int r = 0; r < 4; ++r) {
                const int xo = x0 + m_w + mt * 16 + kg * 4 + r;
                const float v = acc[mt][nt][r];
                outb[(((y << 8) + xo) << 7) + o] = f2b(v);
                lsum[nt] += v; lsq[nt] += v * v;
            }
        }
    }
#pragma unroll
    for (int nt = 0; nt < 4; ++nt) {
        lsum[nt] += __shfl_xor(lsum[nt], 16); lsum[nt] += __shfl_xor(lsum[nt], 32);
        lsq[nt]  += __shfl_xor(lsq[nt], 16);  lsq[nt]  += __shfl_xor(lsq[nt], 32);
    }
    if (kg == 0) {
#pragma unroll
        for (int nt = 0; nt < 4; ++nt) { red_s[w][nt][lo] = lsum[nt]; red_q[w][nt][lo] = lsq[nt]; }
    }
    __syncthreads();
    if (tid < 128) {
        const int o = tid;
        const int half = o >> 6, nt = (o & 63) >> 4, lo2 = o & 15;
        const float s = red_s[half][nt][lo2] + red_s[half + 2][nt][lo2];
        const float q = red_q[half][nt][lo2] + red_q[half + 2][nt][lo2];
        ps[swz * 128 + o] = s;
        pq[swz * 128 + o] = q;
    }
}

// ------------------------------------------- per-channel IN params
__global__ __launch_bounds__(256) void k_stats(
    const float* __restrict__ ps, const float* __restrict__ pq, int R,
    const float* __restrict__ g, const float* __restrict__ be,
    float* __restrict__ scl, float* __restrict__ sft)
{
    const int o = blockIdx.x, tid = threadIdx.x;
    float s = 0.f, q = 0.f;
    for (int r = tid; r < R; r += 256) { s += ps[r * 128 + o]; q += pq[r * 128 + o]; }
#pragma unroll
    for (int off = 32; off; off >>= 1) { s += __shfl_down(s, off); q += __shfl_down(q, off); }
    __shared__ float rs[4], rq[4];
    if ((tid & 63) == 0) { rs[tid >> 6] = s; rq[tid >> 6] = q; }
    __syncthreads();
    if (tid == 0) {
        s = rs[0] + rs[1] + rs[2] + rs[3];
        q = rq[0] + rq[1] + rq[2] + rq[3];
        const float mean = s * (1.f / 65536.f);
        const float var = q * (1.f / 65536.f) - mean * mean;
        const float rstd = rsqrtf(var + 1e-6f);
        const float sc = g[o] * rstd;
        scl[o] = sc;
        sft[o] = be[o] - mean * sc;
    }
}

// ------------------------------------------- norm + ELU: bf16 in -> bf16 out (8 ch/thread)
__global__ __launch_bounds__(256) void k_norm_elu(
    const ushort* __restrict__ in, ushort* __restrict__ out,
    const float* __restrict__ scl, const float* __restrict__ sft)
{
    const int j = blockIdx.x * 256 + threadIdx.x;   // 1048576 groups of 8
    const uint4 pv = ((const uint4*)in)[j];
    const ushort* u = (const ushort*)&pv;
    const int o0 = (j & 15) << 3;
    ushort ro[8];
#pragma unroll
    for (int t = 0; t < 8; ++t) {
        const float x = b2f(u[t]);
        ro[t] = f2b(eluf(x * scl[o0 + t] + sft[o0 + t]));
    }
    ((uint4*)out)[j] = *(const uint4*)ro;
}

// ------------------------------------------- final: out = elu(x1 + norm(h2)), fp32 out
__global__ __launch_bounds__(256) void k_final(
    const ushort* __restrict__ x1b, const ushort* __restrict__ h2b,
    const float* __restrict__ scl, const float* __restrict__ sft,
    float* __restrict__ outp)
{
    const int j = blockIdx.x * 256 + threadIdx.x;   // 1048576 groups of 8
    const uint4 xv = ((const uint4*)x1b)[j];
    const uint4 hv = ((const uint4*)h2b)[j];
    const ushort* xu = (const ushort*)&xv;
    const ushort* hu = (const ushort*)&hv;
    const int o0 = (j & 15) << 3;
    float ro[8];
#pragma unroll
    for (int t = 0; t < 8; ++t) {
        const float a = b2f(xu[t]);
        const float h = b2f(hu[t]);
        ro[t] = eluf(a + h * scl[o0 + t] + sft[o0 + t]);
    }
    ((float4*)outp)[2 * j]     = *(const float4*)&ro[0];
    ((float4*)outp)[2 * j + 1] = *(const float4*)&ro[4];
}

extern "C" void kernel_launch(void* const* d_in, const int* in_sizes, int n_in,
                              void* d_out, int out_size, void* d_ws, size_t ws_size,
                              hipStream_t stream)
{
    const float* msa   = (const float*)d_in[0];
    const float* pairo = (const float*)d_in[1];
    const float* W1    = (const float*)d_in[2];
    const float* b1    = (const float*)d_in[3];
    const float* g_ln  = (const float*)d_in[4];
    const float* be_ln = (const float*)d_in[5];
    const float* W2    = (const float*)d_in[6];
    const float* b2    = (const float*)d_in[7];
    const float* Wc0   = (const float*)d_in[8];
    const float* g0    = (const float*)d_in[9];
    const float* be0   = (const float*)d_in[10];
    const float* Wr1   = (const float*)d_in[11];
    const float* g1    = (const float*)d_in[12];
    const float* be1   = (const float*)d_in[13];
    const float* Wr2   = (const float*)d_in[14];
    const float* g2    = (const float*)d_in[15];
    const float* be2   = (const float*)d_in[16];

    float* ws = (float*)d_ws;
    ushort* xdT   = (ushort*)ws;                    // 262144 f
    float* Ai     = ws + 294912;                    // 32768
    float* Bl     = ws + 327680;                    // 32768
    float* S1     = ws + 360448;                    // 128
    float* S2     = ws + 360576;                    // 128
    float* scl    = ws + 360704;                    // 128
    float* sft    = ws + 360832;                    // 128
    ushort* WCB   = (ushort*)(ws + 360960);         // 16384 f
    ushort* G2swz = (ushort*)(ws + 393728);         // 65536 f
    float* ps     = ws + 590336;                    // 524288
    float* pq     = ws + 1114624;                   // 524288
    ushort* WB1   = (ushort*)(ws + 1638912);        // 73728 f
    ushort* WB2   = (ushort*)(ws + 1712640);        // 73728 f
    float* R1     = ws + 1786368;                   // 8388608 f
    float* R2     = ws + 10174976;                  // 8388608 f
    // R1: [first half] X2b ; [second half] X1b
    ushort* X2b    = (ushort*)R1;
    ushort* X1b    = (ushort*)(R1 + 4194304);
    // R2: [first half] X0b -> H2b ; [second half] Hb
    ushort* X0b = (ushort*)R2;
    ushort* H2b = (ushort*)R2;
    ushort* Hb  = (ushort*)(R2 + 4194304);

    k_prep<<<dim3(4224), dim3(256), 0, stream>>>(
        msa, W1, b1, xdT, W2, g_ln, be_ln, b2, S1, S2, G2swz,
        Wc0, WCB, Ai, Bl, Wr1, WB1, Wr2, WB2);

    k_pairf<<<dim3(2048), dim3(256), 0, stream>>>(
        xdT, G2swz, S1, S2, pairo, Ai, Bl, WCB, X0b, ps, pq);

    k_stats<<<dim3(128), dim3(256), 0, stream>>>(ps, pq, 2048, g0, be0, scl, sft);
    k_norm_elu<<<dim3(4096), dim3(256), 0, stream>>>(X0b, X1b, scl, sft);

    k_conv3x3m<<<dim3(512), dim3(256), 0, stream>>>(X1b, WB1, Hb, ps, pq);
    k_stats<<<dim3(128), dim3(256), 0, stream>>>(ps, pq, 512, g1, be1, scl, sft);
    k_norm_elu<<<dim3(4096), dim3(256), 0, stream>>>(Hb, X2b, scl, sft);

    k_conv3x3m<<<dim3(512), dim3(256), 0, stream>>>(X2b, WB2, H2b, ps, pq);
    k_stats<<<dim3(128), dim3(256), 0, stream>>>(ps, pq, 512, g2, be2, scl, sft);

    k_final<<<dim3(4096), dim3(256), 0, stream>>>(X1b, H2b, scl, sft, (float*)d_out);
}

// Round 21
// 187.916 us; speedup vs baseline: 1.2295x; 1.1954x over previous
//
#include <hip/hip_runtime.h>
#include <hip/hip_bf16.h>
#include <math.h>

// Shapes: B=1, N=64, L=256, nf=64, npj=32, nfo=128
// All GEMM-shaped work on bf16 MFMA (16x16x32). All intermediate activations bf16.
// Fragment conventions (validated rounds 1-20):
//   A-frag: row = lane&15, k = (lane>>4)*8 + j
//   B-frag: col = lane&15, k = (lane>>4)*8 + j
//   C-frag: col = lane&15, row = (lane>>4)*4 + r
// xdT carries xd/8 so outer products are pre-scaled by 1/64 (exact).
// r18: __expf ELU (expm1f was ~75us hidden). r20: conv K-loop barrier-free.
// r21: conv3x3m -> 512 threads (2 waves/SIMD at 1 block/CU) to cover L2/LDS latency;
//      wave grid 2m x 4n, per-block work and traffic unchanged.

typedef __attribute__((ext_vector_type(8))) short bf16x8;
typedef __attribute__((ext_vector_type(4))) float f32x4;

__device__ __forceinline__ float eluf(float x) { return x > 0.f ? x : __expf(x) - 1.f; }
__device__ __forceinline__ ushort f2b(float f) {
    __hip_bfloat16 h = __float2bfloat16(f);
    return *reinterpret_cast<ushort*>(&h);
}
__device__ __forceinline__ float b2f(ushort u) {
    return __uint_as_float(((unsigned)u) << 16);
}

// ================================================================ mega-prologue
__global__ __launch_bounds__(256) void k_prep(
    const float* __restrict__ msa, const float* __restrict__ W1,
    const float* __restrict__ b1, ushort* __restrict__ xdT,
    const float* __restrict__ W2, const float* __restrict__ g_ln,
    const float* __restrict__ be_ln, const float* __restrict__ b2,
    float* __restrict__ S1, float* __restrict__ S2, ushort* __restrict__ G2swz,
    const float* __restrict__ Wc0, ushort* __restrict__ WCB,
    float* __restrict__ Ai, float* __restrict__ Bl,
    const float* __restrict__ Wr1, ushort* __restrict__ WB1,
    const float* __restrict__ Wr2, ushort* __restrict__ WB2)
{
    __shared__ float smem[32 * 65];
    const int b = blockIdx.x, tid = threadIdx.x;
    if (b < 2048) {
        for (int t = tid; t < 2048; t += 256) smem[(t >> 6) * 65 + (t & 63)] = W1[t];
        __syncthreads();
        const int id = b * 256 + tid;
        const int p = id & 31, l = (id >> 5) & 255, n = id >> 13;
        const float* mrow = msa + (((n << 8) + l) << 6);
        const float* wrow = smem + p * 65;
        float s = 0.f;
#pragma unroll 8
        for (int f = 0; f < 64; ++f) s += mrow[f] * wrow[f];
        xdT[(((l << 5) + p) << 6) + n] = f2b((s + b1[p]) * 0.125f);  // xd/8
    } else if (b < 2176) {
        const int o = b - 2048;
        float s1 = 0.f, s2 = 0.f;
        for (int c = tid; c < 1024; c += 256) {
            float w = W2[o * 1024 + c];
            s1 += g_ln[c] * w;
            s2 += be_ln[c] * w;
        }
#pragma unroll
        for (int off = 32; off; off >>= 1) { s1 += __shfl_down(s1, off); s2 += __shfl_down(s2, off); }
        __shared__ float r1[4], r2[4];
        if ((tid & 63) == 0) { r1[tid >> 6] = s1; r2[tid >> 6] = s2; }
        __syncthreads();
        if (tid == 0) {
            S1[o] = r1[0] + r1[1] + r1[2] + r1[3];
            S2[o] = r2[0] + r2[1] + r2[2] + r2[3] + b2[o];
        }
    } else if (b < 2688) {
        const int idx = (b - 2176) * 256 + tid;   // 131072
        const int j = idx & 7, lane = (idx >> 3) & 63, nt = (idx >> 9) & 7, kt = idx >> 12;
        const int k = kt * 32 + (lane >> 4) * 8 + j;
        const int o = nt * 16 + (lane & 15);
        G2swz[idx] = f2b(g_ln[k] * W2[o * 1024 + k]);
    } else if (b < 2816) {
        const int idx = (b - 2688) * 256 + tid;   // 32768
        const int j = idx & 7, lane = (idx >> 3) & 63, nt = (idx >> 9) & 7, ks = idx >> 12;
        const int ic = ks * 32 + (lane >> 4) * 8 + j;
        const int o = nt * 16 + (lane & 15);
        WCB[idx] = f2b(Wc0[o * 512 + ic]);
    } else if (b < 3072) {
        const int r = b - 2816;
        if (tid < 128) {
            const int c = tid;
            float v;
            if (c < 64) {
                float s = 0.f;
                for (int n = 0; n < 64; ++n) s += msa[(((n << 8) + r) << 6) + c];
                v = s * (1.f / 64.f);
            } else {
                v = msa[(r << 6) + (c - 64)];
            }
            smem[c] = v;
        }
        __syncthreads();
        const int o = tid & 127, half = tid >> 7;
        const float* wv = Wc0 + o * 512 + 256 + (half << 7);
        float a = 0.f;
#pragma unroll 4
        for (int c = 0; c < 128; ++c) a += smem[c] * wv[c];
        (half ? Bl : Ai)[r * 128 + o] = a;
    } else if (b < 3648) {
        const int idx = (b - 3072) * 256 + tid;   // 147456
        const int j = idx & 7, lane = (idx >> 3) & 63, nt = (idx >> 9) & 7;
        const int ks = (idx >> 12) & 3, tap = idx >> 14;
        const int ic = ks * 32 + (lane >> 4) * 8 + j;
        const int o = nt * 16 + (lane & 15);
        WB1[idx] = f2b(Wr1[o * 1152 + ic * 9 + tap]);
    } else {
        const int idx = (b - 3648) * 256 + tid;   // 147456
        const int j = idx & 7, lane = (idx >> 3) & 63, nt = (idx >> 9) & 7;
        const int ks = (idx >> 12) & 3, tap = idx >> 14;
        const int ic = ks * 32 + (lane >> 4) * 8 + j;
        const int o = nt * 16 + (lane & 15);
        WB2[idx] = f2b(Wr2[o * 1152 + ic * 9 + tap]);
    }
}

// ================================================================ fused pair + 1x1 conv (r16/r18)
__global__ __launch_bounds__(256, 2) void k_pairf(
    const ushort* __restrict__ xdT, const ushort* __restrict__ G2swz,
    const float* __restrict__ S1, const float* __restrict__ S2,
    const float* __restrict__ pairo, const float* __restrict__ Ai,
    const float* __restrict__ Bl, const ushort* __restrict__ WCB,
    ushort* __restrict__ X0b, float* __restrict__ ps, float* __restrict__ pq)
{
    __shared__ ushort P_lds[32 * 1024];     // 64 KB; pair2 aliased later
    __shared__ float aibl[12 * 128];        // 6 KB
    __shared__ float mus[32], rstds[32];
    __shared__ float red_s[4][2][16], red_q[4][2][16];
    ushort* pair2_lds = P_lds;              // alias (see barriers)
    const int tid = threadIdx.x;
    const int w = tid >> 6, lane = tid & 63;
    const int lo = lane & 15, kg = lane >> 4;
    const int bid = blockIdx.x;
    const int swz = ((bid & 7) << 8) + (bid >> 3);
    const int lb = (swz & 31) << 3;      // 8 l
    const int ib = (swz >> 5) << 2;      // 4 i
    const int m_w = (w >> 1) << 7;
    const int n_w = (w & 1) << 6;

#pragma unroll
    for (int t = tid; t < 1536; t += 256) {
        if (t < 512) aibl[t] = Ai[((ib + (t >> 7)) << 7) + (t & 127)];
        else         aibl[t] = Bl[((lb + ((t - 512) >> 7)) << 7) + (t & 127)];
    }

    f32x4 acc[8][4] = {};
#pragma unroll
    for (int ks = 0; ks < 2; ++ks) {
        bf16x8 a[8], b[4];
#pragma unroll
        for (int mt = 0; mt < 8; ++mt)
            a[mt] = *(const bf16x8*)&xdT[((lb << 5) + m_w + mt * 16 + lo) * 64 + ks * 32 + kg * 8];
#pragma unroll
        for (int nt = 0; nt < 4; ++nt)
            b[nt] = *(const bf16x8*)&xdT[((ib << 5) + n_w + nt * 16 + lo) * 64 + ks * 32 + kg * 8];
#pragma unroll
        for (int mt = 0; mt < 8; ++mt)
#pragma unroll
            for (int nt = 0; nt < 4; ++nt)
                acc[mt][nt] = __builtin_amdgcn_mfma_f32_16x16x32_bf16(a[mt], b[nt], acc[mt][nt], 0, 0, 0);
    }

#pragma unroll
    for (int jj = 0; jj < 2; ++jj) {
#pragma unroll
        for (int ii = 0; ii < 4; ++ii) {
            float s = 0.f, q = 0.f;
#pragma unroll
            for (int dm = 0; dm < 2; ++dm)
#pragma unroll
                for (int dn = 0; dn < 2; ++dn)
#pragma unroll
                    for (int r = 0; r < 4; ++r) {
                        const float v = acc[ii * 2 + dm][jj * 2 + dn][r];
                        s += v; q += v * v;
                    }
#pragma unroll
            for (int off = 1; off < 64; off <<= 1) { s += __shfl_xor(s, off); q += __shfl_xor(q, off); }
            if (lane == 0) {
                const int l_loc = ((w >> 1) << 2) + ii;
                const int i_loc = ((w & 1) << 1) + jj;
                const int px = (i_loc << 3) + l_loc;
                const float mu = s * (1.f / 1024.f);
                const float var = q * (1.f / 1024.f) - mu * mu;
                mus[px] = mu;
                rstds[px] = rsqrtf(var + 1e-5f);
            }
        }
    }
#pragma unroll
    for (int mt = 0; mt < 8; ++mt) {
        const int mrow = m_w + mt * 16;
        const int l_loc = mrow >> 5;
        const int qb = (mrow & 31) + (kg << 2);
#pragma unroll
        for (int nt = 0; nt < 4; ++nt) {
            const int ncol = n_w + nt * 16;
            const int i_loc = ncol >> 5;
            const int p = (ncol & 31) + lo;
            const int px = (i_loc << 3) + l_loc;
            const int L = (p << 6) + (qb << 1);
            const int phys = (px << 11) + (L ^ ((px & 7) << 4) ^ (((L >> 8) & 3) << 4));
            ushort4 pk;
            pk.x = f2b(acc[mt][nt][0]);
            pk.y = f2b(acc[mt][nt][1]);
            pk.z = f2b(acc[mt][nt][2]);
            pk.w = f2b(acc[mt][nt][3]);
            *(ushort4*)((char*)P_lds + phys) = pk;
        }
    }
    __syncthreads();

    f32x4 pacc[2][2] = {};
#pragma unroll 4
    for (int ks = 0; ks < 32; ++ks) {
        const int L0 = (ks << 6) + (kg << 4);
        const int off0 = (L0 ^ ((lo & 7) << 4) ^ (((L0 >> 8) & 3) << 4));
        const bf16x8 a0 = *(const bf16x8*)((const char*)P_lds + (lo << 11) + off0);
        const bf16x8 a1 = *(const bf16x8*)((const char*)P_lds + ((16 + lo) << 11) + off0);
        const bf16x8 b0 = *(const bf16x8*)&G2swz[(((ks << 3) + (w << 1) + 0) * 64 + lane) * 8];
        const bf16x8 b1 = *(const bf16x8*)&G2swz[(((ks << 3) + (w << 1) + 1) * 64 + lane) * 8];
        pacc[0][0] = __builtin_amdgcn_mfma_f32_16x16x32_bf16(a0, b0, pacc[0][0], 0, 0, 0);
        pacc[0][1] = __builtin_amdgcn_mfma_f32_16x16x32_bf16(a0, b1, pacc[0][1], 0, 0, 0);
        pacc[1][0] = __builtin_amdgcn_mfma_f32_16x16x32_bf16(a1, b0, pacc[1][0], 0, 0, 0);
        pacc[1][1] = __builtin_amdgcn_mfma_f32_16x16x32_bf16(a1, b1, pacc[1][1], 0, 0, 0);
    }
    __syncthreads();   // all P reads done -> safe to alias

#pragma unroll
    for (int mt2 = 0; mt2 < 2; ++mt2) {
#pragma unroll
        for (int j = 0; j < 2; ++j) {
            const int o = (((w << 1) + j) << 4) + lo;
            const float s1v = S1[o], s2v = S2[o];
#pragma unroll
            for (int r = 0; r < 4; ++r) {
                const int px = (mt2 << 4) + (kg << 2) + r;
                const float v = rstds[px] * (pacc[mt2][j][r] - mus[px] * s1v) + s2v;
                const int phys = (px << 8) + ((o << 1) ^ ((px & 7) << 4));
                *(ushort*)((char*)pair2_lds + phys) = f2b(v);
            }
        }
    }
    __syncthreads();

    f32x4 cacc[2][2] = {};
#pragma unroll
    for (int ks2 = 0; ks2 < 8; ++ks2) {
        bf16x8 a[2], b[2];
#pragma unroll
        for (int mt = 0; mt < 2; ++mt) {
            const int px = mt * 16 + lo;
            if (ks2 < 4) {
                const int pix = ((ib + (px >> 3)) << 8) + lb + (px & 7);
                const float* base = &pairo[pix * 128 + (ks2 & 3) * 32 + kg * 8];
                const uint4 u0 = *(const uint4*)base;
                const uint4 u1 = *(const uint4*)(base + 4);
                uint4 pk;
                pk.x = __builtin_amdgcn_perm(u0.y, u0.x, 0x07060302);
                pk.y = __builtin_amdgcn_perm(u0.w, u0.z, 0x07060302);
                pk.z = __builtin_amdgcn_perm(u1.y, u1.x, 0x07060302);
                pk.w = __builtin_amdgcn_perm(u1.w, u1.z, 0x07060302);
                a[mt] = *(const bf16x8*)&pk;
            } else {
                const int L0 = ((ks2 & 3) << 6) + (kg << 4);
                const int phys = (px << 8) + (L0 ^ ((px & 7) << 4));
                a[mt] = *(const bf16x8*)((const char*)pair2_lds + phys);
            }
        }
#pragma unroll
        for (int j = 0; j < 2; ++j)
            b[j] = *(const bf16x8*)&WCB[(((ks2 << 3) + (w << 1) + j) * 64 + lane) * 8];
#pragma unroll
        for (int mt = 0; mt < 2; ++mt)
#pragma unroll
            for (int j = 0; j < 2; ++j)
                cacc[mt][j] = __builtin_amdgcn_mfma_f32_16x16x32_bf16(a[mt], b[j], cacc[mt][j], 0, 0, 0);
    }

    float lsum[2] = {0.f, 0.f}, lsq[2] = {0.f, 0.f};
#pragma unroll
    for (int j = 0; j < 2; ++j) {
        const int o = (((w << 1) + j) << 4) + lo;
#pragma unroll
        for (int mt = 0; mt < 2; ++mt) {
#pragma unroll
            for (int r = 0; r < 4; ++r) {
                const int px = mt * 16 + kg * 4 + r;
                const int i_loc = px >> 3, l_loc = px & 7;
                const float v = cacc[mt][j][r] + aibl[(i_loc << 7) + o] + aibl[512 + (l_loc << 7) + o];
                const int pix = ((ib + i_loc) << 8) + lb + l_loc;
                X0b[(pix << 7) + o] = f2b(v);
                lsum[j] += v; lsq[j] += v * v;
            }
        }
    }
#pragma unroll
    for (int j = 0; j < 2; ++j) {
        lsum[j] += __shfl_xor(lsum[j], 16); lsum[j] += __shfl_xor(lsum[j], 32);
        lsq[j]  += __shfl_xor(lsq[j], 16);  lsq[j]  += __shfl_xor(lsq[j], 32);
    }
    if (kg == 0) {
#pragma unroll
        for (int j = 0; j < 2; ++j) { red_s[w][j][lo] = lsum[j]; red_q[w][j][lo] = lsq[j]; }
    }
    __syncthreads();
    if (tid < 128) {
        const int o = tid;
        const int w2 = o >> 5, j2 = (o >> 4) & 1, lo2 = o & 15;
        ps[swz * 128 + o] = red_s[w2][j2][lo2];
        pq[swz * 128 + o] = red_q[w2][j2][lo2];
    }
}

// ================================================================ 3x3 conv v9: 512 thr (2 waves/SIMD),
// A staged in LDS once, B from L2 via 3-slot reg pipeline, zero K-loop barriers.
// Wave grid: mh = w>>2 (2 x 64px), nh = w&3 (4 x 32o). Per wave mt=4, nt=2.
__global__ __launch_bounds__(512, 1) void k_conv3x3m(
    const ushort* __restrict__ Xb, const ushort* __restrict__ WB,
    ushort* __restrict__ outb, float* __restrict__ ps, float* __restrict__ pq)
{
    __shared__ ushort A_lds[3 * 130 * 136];   // 106,080 B (272 B per px)
    __shared__ float red_s[8][2][16], red_q[8][2][16];
    const int tid = threadIdx.x;
    const int w = tid >> 6, lane = tid & 63;
    const int lo = lane & 15, kg = lane >> 4;
    const int mh = w >> 2, nh = w & 3;
    const int m_w = mh << 6;            // 64 px per m half
    const int n4 = nh << 1;             // B row base (2 o-tiles of 16)
    const int bid = blockIdx.x;
    const int swz = ((bid & 7) << 6) + (bid >> 3);
    const int y = swz >> 1;
    const int x0 = (swz & 1) << 7;

    // stage A once (OOB = 0)
    for (int s = tid; s < 6240; s += 512) {
        const int c16 = s & 15;
        const int t2 = s >> 4;
        const int pl = t2 % 130;
        const int ky = t2 / 130;
        const int gx = x0 - 1 + pl;
        const int gy = y - 1 + ky;
        uint4 v = make_uint4(0u, 0u, 0u, 0u);
        if ((unsigned)gx < 256u && (unsigned)gy < 256u)
            v = *(const uint4*)&Xb[(((gy << 8) + gx) << 7) + (c16 << 3)];
        *(uint4*)((char*)A_lds + ky * 35360 + pl * 272 + (c16 << 4)) = v;
    }
    __syncthreads();   // the ONLY barrier before the epilogue

    f32x4 acc[4][2] = {};
    bf16x8 B[3][2];
#define BLOAD(S, SL)                                                                  \
    {                                                                                 \
        _Pragma("unroll")                                                             \
        for (int nt = 0; nt < 2; ++nt)                                                \
            B[SL][nt] = *(const bf16x8*)&WB[(S) * 4096 + (n4 + nt) * 512 + lane * 8]; \
    }
    BLOAD(0, 0);
    BLOAD(1, 1);
#pragma unroll
    for (int s = 0; s < 36; ++s) {
        const int tap = s >> 2, ks = s & 3;
        const int ky = tap / 3, kx = tap % 3;
        if (s + 2 < 36) BLOAD(s + 2, (s + 2) % 3);
        bf16x8 a[4];
#pragma unroll
        for (int mt = 0; mt < 4; ++mt) {
            const int pl = m_w + mt * 16 + lo + kx;
            a[mt] = *(const bf16x8*)((const char*)A_lds + ky * 35360 + pl * 272 + ks * 64 + kg * 16);
        }
#pragma unroll
        for (int mt = 0; mt < 4; ++mt)
#pragma unroll
            for (int nt = 0; nt < 2; ++nt)
                acc[mt][nt] = __builtin_amdgcn_mfma_f32_16x16x32_bf16(a[mt], B[s % 3][nt], acc[mt][nt], 0, 0, 0);
    }
#undef BLOAD

    float lsum[2] = {0.f, 0.f}, lsq[2] = {0.f, 0.f};
#pragma unroll
    for (int nt = 0; nt < 2; ++nt) {
        const int o = (nh << 5) + nt * 16 + lo;
#pragma unroll
        for (int mt = 0; mt < 4; ++mt) {
#pragma unroll
            for (int r = 0; r < 4; ++r) {
                const int xo = x0 + m_w + mt * 16 + kg * 4 + r;
                const float v = acc[mt][nt][r];
                outb[(((y << 8) + xo) << 7) + o] = f2b(v);
                lsum[nt] += v; lsq[nt] += v * v;
            }
        }
    }
#pragma unroll
    for (int nt = 0; nt < 2; ++nt) {
        lsum[nt] += __shfl_xor(lsum[nt], 16); lsum[nt] += __shfl_xor(lsum[nt], 32);
        lsq[nt]  += __shfl_xor(lsq[nt], 16);  lsq[nt]  += __shfl_xor(lsq[nt], 32);
    }
    if (kg == 0) {
#pragma unroll
        for (int nt = 0; nt < 2; ++nt) { red_s[w][nt][lo] = lsum[nt]; red_q[w][nt][lo] = lsq[nt]; }
    }
    __syncthreads();
    if (tid < 128) {
        const int o = tid;
        const int nh2 = o >> 5, nt2 = (o >> 4) & 1, lo2 = o & 15;
        const float s = red_s[nh2][nt2][lo2] + red_s[nh2 + 4][nt2][lo2];
        const float q = red_q[nh2][nt2][lo2] + red_q[nh2 + 4][nt2][lo2];
        ps[swz * 128 + o] = s;
        pq[swz * 128 + o] = q;
    }
}

// ------------------------------------------- per-channel IN params
__global__ __launch_bounds__(256) void k_stats(
    const float* __restrict__ ps, const float* __restrict__ pq, int R,
    const float* __restrict__ g, const float* __restrict__ be,
    float* __restrict__ scl, float* __restrict__ sft)
{
    const int o = blockIdx.x, tid = threadIdx.x;
    float s = 0.f, q = 0.f;
    for (int r = tid; r < R; r += 256) { s += ps[r * 128 + o]; q += pq[r * 128 + o]; }
#pragma unroll
    for (int off = 32; off; off >>= 1) { s += __shfl_down(s, off); q += __shfl_down(q, off); }
    __shared__ float rs[4], rq[4];
    if ((tid & 63) == 0) { rs[tid >> 6] = s; rq[tid >> 6] = q; }
    __syncthreads();
    if (tid == 0) {
        s = rs[0] + rs[1] + rs[2] + rs[3];
        q = rq[0] + rq[1] + rq[2] + rq[3];
        const float mean = s * (1.f / 65536.f);
        const float var = q * (1.f / 65536.f) - mean * mean;
        const float rstd = rsqrtf(var + 1e-6f);
        const float sc = g[o] * rstd;
        scl[o] = sc;
        sft[o] = be[o] - mean * sc;
    }
}

// ------------------------------------------- norm + ELU: bf16 in -> bf16 out (8 ch/thread)
__global__ __launch_bounds__(256) void k_norm_elu(
    const ushort* __restrict__ in, ushort* __restrict__ out,
    const float* __restrict__ scl, const float* __restrict__ sft)
{
    const int j = blockIdx.x * 256 + threadIdx.x;   // 1048576 groups of 8
    const uint4 pv = ((const uint4*)in)[j];
    const ushort* u = (const ushort*)&pv;
    const int o0 = (j & 15) << 3;
    ushort ro[8];
#pragma unroll
    for (int t = 0; t < 8; ++t) {
        const float x = b2f(u[t]);
        ro[t] = f2b(eluf(x * scl[o0 + t] + sft[o0 + t]));
    }
    ((uint4*)out)[j] = *(const uint4*)ro;
}

// ------------------------------------------- final: out = elu(x1 + norm(h2)), fp32 out
__global__ __launch_bounds__(256) void k_final(
    const ushort* __restrict__ x1b, const ushort* __restrict__ h2b,
    const float* __restrict__ scl, const float* __restrict__ sft,
    float* __restrict__ outp)
{
    const int j = blockIdx.x * 256 + threadIdx.x;   // 1048576 groups of 8
    const uint4 xv = ((const uint4*)x1b)[j];
    const uint4 hv = ((const uint4*)h2b)[j];
    const ushort* xu = (const ushort*)&xv;
    const ushort* hu = (const ushort*)&hv;
    const int o0 = (j & 15) << 3;
    float ro[8];
#pragma unroll
    for (int t = 0; t < 8; ++t) {
        const float a = b2f(xu[t]);
        const float h = b2f(hu[t]);
        ro[t] = eluf(a + h * scl[o0 + t] + sft[o0 + t]);
    }
    ((float4*)outp)[2 * j]     = *(const float4*)&ro[0];
    ((float4*)outp)[2 * j + 1] = *(const float4*)&ro[4];
}

extern "C" void kernel_launch(void* const* d_in, const int* in_sizes, int n_in,
                              void* d_out, int out_size, void* d_ws, size_t ws_size,
                              hipStream_t stream)
{
    const float* msa   = (const float*)d_in[0];
    const float* pairo = (const float*)d_in[1];
    const float* W1    = (const float*)d_in[2];
    const float* b1    = (const float*)d_in[3];
    const float* g_ln  = (const float*)d_in[4];
    const float* be_ln = (const float*)d_in[5];
    const float* W2    = (const float*)d_in[6];
    const float* b2    = (const float*)d_in[7];
    const float* Wc0   = (const float*)d_in[8];
    const float* g0    = (const float*)d_in[9];
    const float* be0   = (const float*)d_in[10];
    const float* Wr1   = (const float*)d_in[11];
    const float* g1    = (const float*)d_in[12];
    const float* be1   = (const float*)d_in[13];
    const float* Wr2   = (const float*)d_in[14];
    const float* g2    = (const float*)d_in[15];
    const float* be2   = (const float*)d_in[16];

    float* ws = (float*)d_ws;
    ushort* xdT   = (ushort*)ws;                    // 262144 f
    float* Ai     = ws + 294912;                    // 32768
    float* Bl     = ws + 327680;                    // 32768
    float* S1     = ws + 360448;                    // 128
    float* S2     = ws + 360576;                    // 128
    float* scl    = ws + 360704;                    // 128
    float* sft    = ws + 360832;                    // 128
    ushort* WCB   = (ushort*)(ws + 360960);         // 16384 f
    ushort* G2swz = (ushort*)(ws + 393728);         // 65536 f
    float* ps     = ws + 590336;                    // 524288
    float* pq     = ws + 1114624;                   // 524288
    ushort* WB1   = (ushort*)(ws + 1638912);        // 73728 f
    ushort* WB2   = (ushort*)(ws + 1712640);        // 73728 f
    float* R1     = ws + 1786368;                   // 8388608 f
    float* R2     = ws + 10174976;                  // 8388608 f
    // R1: [first half] X2b ; [second half] X1b
    ushort* X2b    = (ushort*)R1;
    ushort* X1b    = (ushort*)(R1 + 4194304);
    // R2: [first half] X0b -> H2b ; [second half] Hb
    ushort* X0b = (ushort*)R2;
    ushort* H2b = (ushort*)R2;
    ushort* Hb  = (ushort*)(R2 + 4194304);

    k_prep<<<dim3(4224), dim3(256), 0, stream>>>(
        msa, W1, b1, xdT, W2, g_ln, be_ln, b2, S1, S2, G2swz,
        Wc0, WCB, Ai, Bl, Wr1, WB1, Wr2, WB2);

    k_pairf<<<dim3(2048), dim3(256), 0, stream>>>(
        xdT, G2swz, S1, S2, pairo, Ai, Bl, WCB, X0b, ps, pq);

    k_stats<<<dim3(128), dim3(256), 0, stream>>>(ps, pq, 2048, g0, be0, scl, sft);
    k_norm_elu<<<dim3(4096), dim3(256), 0, stream>>>(X0b, X1b, scl, sft);

    k_conv3x3m<<<dim3(512), dim3(512), 0, stream>>>(X1b, WB1, Hb, ps, pq);
    k_stats<<<dim3(128), dim3(256), 0, stream>>>(ps, pq, 512, g1, be1, scl, sft);
    k_norm_elu<<<dim3(4096), dim3(256), 0, stream>>>(Hb, X2b, scl, sft);

    k_conv3x3m<<<dim3(512), dim3(512), 0, stream>>>(X2b, WB2, H2b, ps, pq);
    k_stats<<<dim3(128), dim3(256), 0, stream>>>(ps, pq, 512, g2, be2, scl, sft);

    k_final<<<dim3(4096), dim3(256), 0, stream>>>(X1b, H2b, scl, sft, (float*)d_out);
}

// Round 22
// 185.653 us; speedup vs baseline: 1.2445x; 1.0122x over previous
//
#include <hip/hip_runtime.h>
#include <hip/hip_bf16.h>
#include <math.h>

// Shapes: B=1, N=64, L=256, nf=64, npj=32, nfo=128
// All GEMM-shaped work on bf16 MFMA (16x16x32). All intermediate activations bf16.
// Fragment conventions (validated rounds 1-21):
//   A-frag: row = lane&15, k = (lane>>4)*8 + j
//   B-frag: col = lane&15, k = (lane>>4)*8 + j
//   C-frag: col = lane&15, row = (lane>>4)*4 + r
// xdT carries xd/8 so outer products are pre-scaled by 1/64 (exact).
// r18: __expf ELU. r20: conv K-loop barrier-free. r21: conv at 512 thr (2 waves/SIMD).
// r22: norm+ELU fused into conv staging (cheap now at 2 waves/SIMD; scl/sft in LDS);
//      norm_elu dispatches deleted; k_final recomputes X1 from X0b.

typedef __attribute__((ext_vector_type(8))) short bf16x8;
typedef __attribute__((ext_vector_type(4))) float f32x4;

__device__ __forceinline__ float eluf(float x) { return x > 0.f ? x : __expf(x) - 1.f; }
__device__ __forceinline__ ushort f2b(float f) {
    __hip_bfloat16 h = __float2bfloat16(f);
    return *reinterpret_cast<ushort*>(&h);
}
__device__ __forceinline__ float b2f(ushort u) {
    return __uint_as_float(((unsigned)u) << 16);
}

// ================================================================ mega-prologue
__global__ __launch_bounds__(256) void k_prep(
    const float* __restrict__ msa, const float* __restrict__ W1,
    const float* __restrict__ b1, ushort* __restrict__ xdT,
    const float* __restrict__ W2, const float* __restrict__ g_ln,
    const float* __restrict__ be_ln, const float* __restrict__ b2,
    float* __restrict__ S1, float* __restrict__ S2, ushort* __restrict__ G2swz,
    const float* __restrict__ Wc0, ushort* __restrict__ WCB,
    float* __restrict__ Ai, float* __restrict__ Bl,
    const float* __restrict__ Wr1, ushort* __restrict__ WB1,
    const float* __restrict__ Wr2, ushort* __restrict__ WB2)
{
    __shared__ float smem[32 * 65];
    const int b = blockIdx.x, tid = threadIdx.x;
    if (b < 2048) {
        for (int t = tid; t < 2048; t += 256) smem[(t >> 6) * 65 + (t & 63)] = W1[t];
        __syncthreads();
        const int id = b * 256 + tid;
        const int p = id & 31, l = (id >> 5) & 255, n = id >> 13;
        const float* mrow = msa + (((n << 8) + l) << 6);
        const float* wrow = smem + p * 65;
        float s = 0.f;
#pragma unroll 8
        for (int f = 0; f < 64; ++f) s += mrow[f] * wrow[f];
        xdT[(((l << 5) + p) << 6) + n] = f2b((s + b1[p]) * 0.125f);  // xd/8
    } else if (b < 2176) {
        const int o = b - 2048;
        float s1 = 0.f, s2 = 0.f;
        for (int c = tid; c < 1024; c += 256) {
            float w = W2[o * 1024 + c];
            s1 += g_ln[c] * w;
            s2 += be_ln[c] * w;
        }
#pragma unroll
        for (int off = 32; off; off >>= 1) { s1 += __shfl_down(s1, off); s2 += __shfl_down(s2, off); }
        __shared__ float r1[4], r2[4];
        if ((tid & 63) == 0) { r1[tid >> 6] = s1; r2[tid >> 6] = s2; }
        __syncthreads();
        if (tid == 0) {
            S1[o] = r1[0] + r1[1] + r1[2] + r1[3];
            S2[o] = r2[0] + r2[1] + r2[2] + r2[3] + b2[o];
        }
    } else if (b < 2688) {
        const int idx = (b - 2176) * 256 + tid;   // 131072
        const int j = idx & 7, lane = (idx >> 3) & 63, nt = (idx >> 9) & 7, kt = idx >> 12;
        const int k = kt * 32 + (lane >> 4) * 8 + j;
        const int o = nt * 16 + (lane & 15);
        G2swz[idx] = f2b(g_ln[k] * W2[o * 1024 + k]);
    } else if (b < 2816) {
        const int idx = (b - 2688) * 256 + tid;   // 32768
        const int j = idx & 7, lane = (idx >> 3) & 63, nt = (idx >> 9) & 7, ks = idx >> 12;
        const int ic = ks * 32 + (lane >> 4) * 8 + j;
        const int o = nt * 16 + (lane & 15);
        WCB[idx] = f2b(Wc0[o * 512 + ic]);
    } else if (b < 3072) {
        const int r = b - 2816;
        if (tid < 128) {
            const int c = tid;
            float v;
            if (c < 64) {
                float s = 0.f;
                for (int n = 0; n < 64; ++n) s += msa[(((n << 8) + r) << 6) + c];
                v = s * (1.f / 64.f);
            } else {
                v = msa[(r << 6) + (c - 64)];
            }
            smem[c] = v;
        }
        __syncthreads();
        const int o = tid & 127, half = tid >> 7;
        const float* wv = Wc0 + o * 512 + 256 + (half << 7);
        float a = 0.f;
#pragma unroll 4
        for (int c = 0; c < 128; ++c) a += smem[c] * wv[c];
        (half ? Bl : Ai)[r * 128 + o] = a;
    } else if (b < 3648) {
        const int idx = (b - 3072) * 256 + tid;   // 147456
        const int j = idx & 7, lane = (idx >> 3) & 63, nt = (idx >> 9) & 7;
        const int ks = (idx >> 12) & 3, tap = idx >> 14;
        const int ic = ks * 32 + (lane >> 4) * 8 + j;
        const int o = nt * 16 + (lane & 15);
        WB1[idx] = f2b(Wr1[o * 1152 + ic * 9 + tap]);
    } else {
        const int idx = (b - 3648) * 256 + tid;   // 147456
        const int j = idx & 7, lane = (idx >> 3) & 63, nt = (idx >> 9) & 7;
        const int ks = (idx >> 12) & 3, tap = idx >> 14;
        const int ic = ks * 32 + (lane >> 4) * 8 + j;
        const int o = nt * 16 + (lane & 15);
        WB2[idx] = f2b(Wr2[o * 1152 + ic * 9 + tap]);
    }
}

// ================================================================ fused pair + 1x1 conv (r16/r18)
__global__ __launch_bounds__(256, 2) void k_pairf(
    const ushort* __restrict__ xdT, const ushort* __restrict__ G2swz,
    const float* __restrict__ S1, const float* __restrict__ S2,
    const float* __restrict__ pairo, const float* __restrict__ Ai,
    const float* __restrict__ Bl, const ushort* __restrict__ WCB,
    ushort* __restrict__ X0b, float* __restrict__ ps, float* __restrict__ pq)
{
    __shared__ ushort P_lds[32 * 1024];     // 64 KB; pair2 aliased later
    __shared__ float aibl[12 * 128];        // 6 KB
    __shared__ float mus[32], rstds[32];
    __shared__ float red_s[4][2][16], red_q[4][2][16];
    ushort* pair2_lds = P_lds;              // alias (see barriers)
    const int tid = threadIdx.x;
    const int w = tid >> 6, lane = tid & 63;
    const int lo = lane & 15, kg = lane >> 4;
    const int bid = blockIdx.x;
    const int swz = ((bid & 7) << 8) + (bid >> 3);
    const int lb = (swz & 31) << 3;      // 8 l
    const int ib = (swz >> 5) << 2;      // 4 i
    const int m_w = (w >> 1) << 7;
    const int n_w = (w & 1) << 6;

#pragma unroll
    for (int t = tid; t < 1536; t += 256) {
        if (t < 512) aibl[t] = Ai[((ib + (t >> 7)) << 7) + (t & 127)];
        else         aibl[t] = Bl[((lb + ((t - 512) >> 7)) << 7) + (t & 127)];
    }

    f32x4 acc[8][4] = {};
#pragma unroll
    for (int ks = 0; ks < 2; ++ks) {
        bf16x8 a[8], b[4];
#pragma unroll
        for (int mt = 0; mt < 8; ++mt)
            a[mt] = *(const bf16x8*)&xdT[((lb << 5) + m_w + mt * 16 + lo) * 64 + ks * 32 + kg * 8];
#pragma unroll
        for (int nt = 0; nt < 4; ++nt)
            b[nt] = *(const bf16x8*)&xdT[((ib << 5) + n_w + nt * 16 + lo) * 64 + ks * 32 + kg * 8];
#pragma unroll
        for (int mt = 0; mt < 8; ++mt)
#pragma unroll
            for (int nt = 0; nt < 4; ++nt)
                acc[mt][nt] = __builtin_amdgcn_mfma_f32_16x16x32_bf16(a[mt], b[nt], acc[mt][nt], 0, 0, 0);
    }

#pragma unroll
    for (int jj = 0; jj < 2; ++jj) {
#pragma unroll
        for (int ii = 0; ii < 4; ++ii) {
            float s = 0.f, q = 0.f;
#pragma unroll
            for (int dm = 0; dm < 2; ++dm)
#pragma unroll
                for (int dn = 0; dn < 2; ++dn)
#pragma unroll
                    for (int r = 0; r < 4; ++r) {
                        const float v = acc[ii * 2 + dm][jj * 2 + dn][r];
                        s += v; q += v * v;
                    }
#pragma unroll
            for (int off = 1; off < 64; off <<= 1) { s += __shfl_xor(s, off); q += __shfl_xor(q, off); }
            if (lane == 0) {
                const int l_loc = ((w >> 1) << 2) + ii;
                const int i_loc = ((w & 1) << 1) + jj;
                const int px = (i_loc << 3) + l_loc;
                const float mu = s * (1.f / 1024.f);
                const float var = q * (1.f / 1024.f) - mu * mu;
                mus[px] = mu;
                rstds[px] = rsqrtf(var + 1e-5f);
            }
        }
    }
#pragma unroll
    for (int mt = 0; mt < 8; ++mt) {
        const int mrow = m_w + mt * 16;
        const int l_loc = mrow >> 5;
        const int qb = (mrow & 31) + (kg << 2);
#pragma unroll
        for (int nt = 0; nt < 4; ++nt) {
            const int ncol = n_w + nt * 16;
            const int i_loc = ncol >> 5;
            const int p = (ncol & 31) + lo;
            const int px = (i_loc << 3) + l_loc;
            const int L = (p << 6) + (qb << 1);
            const int phys = (px << 11) + (L ^ ((px & 7) << 4) ^ (((L >> 8) & 3) << 4));
            ushort4 pk;
            pk.x = f2b(acc[mt][nt][0]);
            pk.y = f2b(acc[mt][nt][1]);
            pk.z = f2b(acc[mt][nt][2]);
            pk.w = f2b(acc[mt][nt][3]);
            *(ushort4*)((char*)P_lds + phys) = pk;
        }
    }
    __syncthreads();

    f32x4 pacc[2][2] = {};
#pragma unroll 4
    for (int ks = 0; ks < 32; ++ks) {
        const int L0 = (ks << 6) + (kg << 4);
        const int off0 = (L0 ^ ((lo & 7) << 4) ^ (((L0 >> 8) & 3) << 4));
        const bf16x8 a0 = *(const bf16x8*)((const char*)P_lds + (lo << 11) + off0);
        const bf16x8 a1 = *(const bf16x8*)((const char*)P_lds + ((16 + lo) << 11) + off0);
        const bf16x8 b0 = *(const bf16x8*)&G2swz[(((ks << 3) + (w << 1) + 0) * 64 + lane) * 8];
        const bf16x8 b1 = *(const bf16x8*)&G2swz[(((ks << 3) + (w << 1) + 1) * 64 + lane) * 8];
        pacc[0][0] = __builtin_amdgcn_mfma_f32_16x16x32_bf16(a0, b0, pacc[0][0], 0, 0, 0);
        pacc[0][1] = __builtin_amdgcn_mfma_f32_16x16x32_bf16(a0, b1, pacc[0][1], 0, 0, 0);
        pacc[1][0] = __builtin_amdgcn_mfma_f32_16x16x32_bf16(a1, b0, pacc[1][0], 0, 0, 0);
        pacc[1][1] = __builtin_amdgcn_mfma_f32_16x16x32_bf16(a1, b1, pacc[1][1], 0, 0, 0);
    }
    __syncthreads();   // all P reads done -> safe to alias

#pragma unroll
    for (int mt2 = 0; mt2 < 2; ++mt2) {
#pragma unroll
        for (int j = 0; j < 2; ++j) {
            const int o = (((w << 1) + j) << 4) + lo;
            const float s1v = S1[o], s2v = S2[o];
#pragma unroll
            for (int r = 0; r < 4; ++r) {
                const int px = (mt2 << 4) + (kg << 2) + r;
                const float v = rstds[px] * (pacc[mt2][j][r] - mus[px] * s1v) + s2v;
                const int phys = (px << 8) + ((o << 1) ^ ((px & 7) << 4));
                *(ushort*)((char*)pair2_lds + phys) = f2b(v);
            }
        }
    }
    __syncthreads();

    f32x4 cacc[2][2] = {};
#pragma unroll
    for (int ks2 = 0; ks2 < 8; ++ks2) {
        bf16x8 a[2], b[2];
#pragma unroll
        for (int mt = 0; mt < 2; ++mt) {
            const int px = mt * 16 + lo;
            if (ks2 < 4) {
                const int pix = ((ib + (px >> 3)) << 8) + lb + (px & 7);
                const float* base = &pairo[pix * 128 + (ks2 & 3) * 32 + kg * 8];
                const uint4 u0 = *(const uint4*)base;
                const uint4 u1 = *(const uint4*)(base + 4);
                uint4 pk;
                pk.x = __builtin_amdgcn_perm(u0.y, u0.x, 0x07060302);
                pk.y = __builtin_amdgcn_perm(u0.w, u0.z, 0x07060302);
                pk.z = __builtin_amdgcn_perm(u1.y, u1.x, 0x07060302);
                pk.w = __builtin_amdgcn_perm(u1.w, u1.z, 0x07060302);
                a[mt] = *(const bf16x8*)&pk;
            } else {
                const int L0 = ((ks2 & 3) << 6) + (kg << 4);
                const int phys = (px << 8) + (L0 ^ ((px & 7) << 4));
                a[mt] = *(const bf16x8*)((const char*)pair2_lds + phys);
            }
        }
#pragma unroll
        for (int j = 0; j < 2; ++j)
            b[j] = *(const bf16x8*)&WCB[(((ks2 << 3) + (w << 1) + j) * 64 + lane) * 8];
#pragma unroll
        for (int mt = 0; mt < 2; ++mt)
#pragma unroll
            for (int j = 0; j < 2; ++j)
                cacc[mt][j] = __builtin_amdgcn_mfma_f32_16x16x32_bf16(a[mt], b[j], cacc[mt][j], 0, 0, 0);
    }

    float lsum[2] = {0.f, 0.f}, lsq[2] = {0.f, 0.f};
#pragma unroll
    for (int j = 0; j < 2; ++j) {
        const int o = (((w << 1) + j) << 4) + lo;
#pragma unroll
        for (int mt = 0; mt < 2; ++mt) {
#pragma unroll
            for (int r = 0; r < 4; ++r) {
                const int px = mt * 16 + kg * 4 + r;
                const int i_loc = px >> 3, l_loc = px & 7;
                const float v = cacc[mt][j][r] + aibl[(i_loc << 7) + o] + aibl[512 + (l_loc << 7) + o];
                const int pix = ((ib + i_loc) << 8) + lb + l_loc;
                X0b[(pix << 7) + o] = f2b(v);
                lsum[j] += v; lsq[j] += v * v;
            }
        }
    }
#pragma unroll
    for (int j = 0; j < 2; ++j) {
        lsum[j] += __shfl_xor(lsum[j], 16); lsum[j] += __shfl_xor(lsum[j], 32);
        lsq[j]  += __shfl_xor(lsq[j], 16);  lsq[j]  += __shfl_xor(lsq[j], 32);
    }
    if (kg == 0) {
#pragma unroll
        for (int j = 0; j < 2; ++j) { red_s[w][j][lo] = lsum[j]; red_q[w][j][lo] = lsq[j]; }
    }
    __syncthreads();
    if (tid < 128) {
        const int o = tid;
        const int w2 = o >> 5, j2 = (o >> 4) & 1, lo2 = o & 15;
        ps[swz * 128 + o] = red_s[w2][j2][lo2];
        pq[swz * 128 + o] = red_q[w2][j2][lo2];
    }
}

// ================================================================ 3x3 conv v10: 512 thr (2 waves/SIMD),
// A staged in LDS with FUSED norm+ELU (scl/sft LDS-cached), B via 3-slot reg pipeline,
// zero K-loop barriers. OOB stays exact 0 (pad-after-norm semantics).
__global__ __launch_bounds__(512, 1) void k_conv3x3m(
    const ushort* __restrict__ Xb, const ushort* __restrict__ WB,
    const float* __restrict__ scl, const float* __restrict__ sft,
    ushort* __restrict__ outb, float* __restrict__ ps, float* __restrict__ pq)
{
    __shared__ ushort A_lds[3 * 130 * 136];   // 106,080 B (272 B per px)
    __shared__ float red_s[8][2][16], red_q[8][2][16];
    __shared__ float sclS[128], sftS[128];
    const int tid = threadIdx.x;
    const int w = tid >> 6, lane = tid & 63;
    const int lo = lane & 15, kg = lane >> 4;
    const int mh = w >> 2, nh = w & 3;
    const int m_w = mh << 6;            // 64 px per m half
    const int n4 = nh << 1;             // B row base (2 o-tiles of 16)
    const int bid = blockIdx.x;
    const int swz = ((bid & 7) << 6) + (bid >> 3);
    const int y = swz >> 1;
    const int x0 = (swz & 1) << 7;

    if (tid < 128) { sclS[tid] = scl[tid]; sftS[tid] = sft[tid]; }
    __syncthreads();

    // stage A once with fused norm+ELU (OOB = 0)
    for (int s = tid; s < 6240; s += 512) {
        const int c16 = s & 15;
        const int t2 = s >> 4;
        const int pl = t2 % 130;
        const int ky = t2 / 130;
        const int gx = x0 - 1 + pl;
        const int gy = y - 1 + ky;
        uint4 v = make_uint4(0u, 0u, 0u, 0u);
        if ((unsigned)gx < 256u && (unsigned)gy < 256u) {
            const uint4 raw = *(const uint4*)&Xb[(((gy << 8) + gx) << 7) + (c16 << 3)];
            const ushort* u = (const ushort*)&raw;
            const int c0 = c16 << 3;
            ushort ro[8];
#pragma unroll
            for (int t = 0; t < 8; ++t)
                ro[t] = f2b(eluf(b2f(u[t]) * sclS[c0 + t] + sftS[c0 + t]));
            v = *(const uint4*)ro;
        }
        *(uint4*)((char*)A_lds + ky * 35360 + pl * 272 + (c16 << 4)) = v;
    }
    __syncthreads();   // the ONLY barrier before the epilogue

    f32x4 acc[4][2] = {};
    bf16x8 B[3][2];
#define BLOAD(S, SL)                                                                  \
    {                                                                                 \
        _Pragma("unroll")                                                             \
        for (int nt = 0; nt < 2; ++nt)                                                \
            B[SL][nt] = *(const bf16x8*)&WB[(S) * 4096 + (n4 + nt) * 512 + lane * 8]; \
    }
    BLOAD(0, 0);
    BLOAD(1, 1);
#pragma unroll
    for (int s = 0; s < 36; ++s) {
        const int tap = s >> 2, ks = s & 3;
        const int ky = tap / 3, kx = tap % 3;
        if (s + 2 < 36) BLOAD(s + 2, (s + 2) % 3);
        bf16x8 a[4];
#pragma unroll
        for (int mt = 0; mt < 4; ++mt) {
            const int pl = m_w + mt * 16 + lo + kx;
            a[mt] = *(const bf16x8*)((const char*)A_lds + ky * 35360 + pl * 272 + ks * 64 + kg * 16);
        }
#pragma unroll
        for (int mt = 0; mt < 4; ++mt)
#pragma unroll
            for (int nt = 0; nt < 2; ++nt)
                acc[mt][nt] = __builtin_amdgcn_mfma_f32_16x16x32_bf16(a[mt], B[s % 3][nt], acc[mt][nt], 0, 0, 0);
    }
#undef BLOAD

    float lsum[2] = {0.f, 0.f}, lsq[2] = {0.f, 0.f};
#pragma unroll
    for (int nt = 0; nt < 2; ++nt) {
        const int o = (nh << 5) + nt * 16 + lo;
#pragma unroll
        for (int mt = 0; mt < 4; ++mt) {
#pragma unroll
            for (int r = 0; r < 4; ++r) {
                const int xo = x0 + m_w + mt * 16 + kg * 4 + r;
                const float v = acc[mt][nt][r];
                outb[(((y << 8) + xo) << 7) + o] = f2b(v);
                lsum[nt] += v; lsq[nt] += v * v;
            }
        }
    }
#pragma unroll
    for (int nt = 0; nt < 2; ++nt) {
        lsum[nt] += __shfl_xor(lsum[nt], 16); lsum[nt] += __shfl_xor(lsum[nt], 32);
        lsq[nt]  += __shfl_xor(lsq[nt], 16);  lsq[nt]  += __shfl_xor(lsq[nt], 32);
    }
    if (kg == 0) {
#pragma unroll
        for (int nt = 0; nt < 2; ++nt) { red_s[w][nt][lo] = lsum[nt]; red_q[w][nt][lo] = lsq[nt]; }
    }
    __syncthreads();
    if (tid < 128) {
        const int o = tid;
        const int nh2 = o >> 5, nt2 = (o >> 4) & 1, lo2 = o & 15;
        const float s = red_s[nh2][nt2][lo2] + red_s[nh2 + 4][nt2][lo2];
        const float q = red_q[nh2][nt2][lo2] + red_q[nh2 + 4][nt2][lo2];
        ps[swz * 128 + o] = s;
        pq[swz * 128 + o] = q;
    }
}

// ------------------------------------------- per-channel IN params
__global__ __launch_bounds__(256) void k_stats(
    const float* __restrict__ ps, const float* __restrict__ pq, int R,
    const float* __restrict__ g, const float* __restrict__ be,
    float* __restrict__ scl, float* __restrict__ sft)
{
    const int o = blockIdx.x, tid = threadIdx.x;
    float s = 0.f, q = 0.f;
    for (int r = tid; r < R; r += 256) { s += ps[r * 128 + o]; q += pq[r * 128 + o]; }
#pragma unroll
    for (int off = 32; off; off >>= 1) { s += __shfl_down(s, off); q += __shfl_down(q, off); }
    __shared__ float rs[4], rq[4];
    if ((tid & 63) == 0) { rs[tid >> 6] = s; rq[tid >> 6] = q; }
    __syncthreads();
    if (tid == 0) {
        s = rs[0] + rs[1] + rs[2] + rs[3];
        q = rq[0] + rq[1] + rq[2] + rq[3];
        const float mean = s * (1.f / 65536.f);
        const float var = q * (1.f / 65536.f) - mean * mean;
        const float rstd = rsqrtf(var + 1e-6f);
        const float sc = g[o] * rstd;
        scl[o] = sc;
        sft[o] = be[o] - mean * sc;
    }
}

// ------------------------------------------- final: out = elu(elu(x0*s0+f0) + h2*s2+f2), fp32
__global__ __launch_bounds__(256) void k_final(
    const ushort* __restrict__ x0b, const ushort* __restrict__ h2b,
    const float* __restrict__ scl0, const float* __restrict__ sft0,
    const float* __restrict__ scl2, const float* __restrict__ sft2,
    float* __restrict__ outp)
{
    const int j = blockIdx.x * 256 + threadIdx.x;   // 1048576 groups of 8
    const uint4 xv = ((const uint4*)x0b)[j];
    const uint4 hv = ((const uint4*)h2b)[j];
    const ushort* xu = (const ushort*)&xv;
    const ushort* hu = (const ushort*)&hv;
    const int o0 = (j & 15) << 3;
    float ro[8];
#pragma unroll
    for (int t = 0; t < 8; ++t) {
        const float x1 = eluf(b2f(xu[t]) * scl0[o0 + t] + sft0[o0 + t]);
        const float h = b2f(hu[t]);
        ro[t] = eluf(x1 + h * scl2[o0 + t] + sft2[o0 + t]);
    }
    ((float4*)outp)[2 * j]     = *(const float4*)&ro[0];
    ((float4*)outp)[2 * j + 1] = *(const float4*)&ro[4];
}

extern "C" void kernel_launch(void* const* d_in, const int* in_sizes, int n_in,
                              void* d_out, int out_size, void* d_ws, size_t ws_size,
                              hipStream_t stream)
{
    const float* msa   = (const float*)d_in[0];
    const float* pairo = (const float*)d_in[1];
    const float* W1    = (const float*)d_in[2];
    const float* b1    = (const float*)d_in[3];
    const float* g_ln  = (const float*)d_in[4];
    const float* be_ln = (const float*)d_in[5];
    const float* W2    = (const float*)d_in[6];
    const float* b2    = (const float*)d_in[7];
    const float* Wc0   = (const float*)d_in[8];
    const float* g0    = (const float*)d_in[9];
    const float* be0   = (const float*)d_in[10];
    const float* Wr1   = (const float*)d_in[11];
    const float* g1    = (const float*)d_in[12];
    const float* be1   = (const float*)d_in[13];
    const float* Wr2   = (const float*)d_in[14];
    const float* g2    = (const float*)d_in[15];
    const float* be2   = (const float*)d_in[16];

    float* ws = (float*)d_ws;
    ushort* xdT   = (ushort*)ws;                    // 262144 f
    float* Ai     = ws + 294912;                    // 32768
    float* Bl     = ws + 327680;                    // 32768
    float* S1     = ws + 360448;                    // 128
    float* S2     = ws + 360576;                    // 128
    float* scl0   = ws + 360704;                    // 128
    float* sft0   = ws + 360832;                    // 128
    float* scl1   = ws + 360960;                    // 128
    float* sft1   = ws + 361088;                    // 128
    float* scl2   = ws + 361216;                    // 128
    float* sft2   = ws + 361344;                    // 128
    ushort* WCB   = (ushort*)(ws + 361472);         // 16384 f
    ushort* G2swz = (ushort*)(ws + 393728);         // 65536 f
    float* ps     = ws + 590336;                    // 524288
    float* pq     = ws + 1114624;                   // 524288
    ushort* WB1   = (ushort*)(ws + 1638912);        // 73728 f
    ushort* WB2   = (ushort*)(ws + 1712640);        // 73728 f
    float* R1     = ws + 1786368;                   // 8388608 f
    float* R2     = ws + 10174976;                  // 8388608 f
    ushort* H2b = (ushort*)R1;                      // R1 lo
    ushort* X0b = (ushort*)R2;                      // R2 lo (persists to k_final)
    ushort* Hb  = (ushort*)(R2 + 4194304);          // R2 hi

    k_prep<<<dim3(4224), dim3(256), 0, stream>>>(
        msa, W1, b1, xdT, W2, g_ln, be_ln, b2, S1, S2, G2swz,
        Wc0, WCB, Ai, Bl, Wr1, WB1, Wr2, WB2);

    k_pairf<<<dim3(2048), dim3(256), 0, stream>>>(
        xdT, G2swz, S1, S2, pairo, Ai, Bl, WCB, X0b, ps, pq);

    k_stats<<<dim3(128), dim3(256), 0, stream>>>(ps, pq, 2048, g0, be0, scl0, sft0);

    k_conv3x3m<<<dim3(512), dim3(512), 0, stream>>>(X0b, WB1, scl0, sft0, Hb, ps, pq);
    k_stats<<<dim3(128), dim3(256), 0, stream>>>(ps, pq, 512, g1, be1, scl1, sft1);

    k_conv3x3m<<<dim3(512), dim3(512), 0, stream>>>(Hb, WB2, scl1, sft1, H2b, ps, pq);
    k_stats<<<dim3(128), dim3(256), 0, stream>>>(ps, pq, 512, g2, be2, scl2, sft2);

    k_final<<<dim3(4096), dim3(256), 0, stream>>>(X0b, H2b, scl0, sft0, scl2, sft2, (float*)d_out);
}